// Round 13
// baseline (214.555 us; speedup 1.0000x reference)
//
#include <hip/hip_runtime.h>
#include <cfloat>
#include <math.h>

// Exact-replication KNN (k=10, +self) + rank-column gather max-pool.
// NUMERICS FROZEN (R3 pass, absmax 0.0): fp32 chains
//   sq  = fma(z,z, fma(y,y, rn(x*x)))
//   dot = fma(z,z', fma(y,y', rn(x*x')))
//   d   = fma(dot, -2, rn(sq_i+sq_j))    [== rn(sum - rn(2*dot)), 2*dot exact]
// Selection order = jax top_k = ascending lexicographic (d, orig_idx) —
// proven order-independent in R8/R9 (absmax 0.0, nondeterministic scatter).
//
// Round 23: TILE 128 -> 64 (NTILES 256). R22's per-query gate helped only
// slightly (FETCH unchanged -> few tiles pruned): the tail's survivor set
// is genuine, so the lever is points-scanned PER surviving tile. 64-pt
// tiles halve the boundary-quantization waste, tighten every AABB (higher
// lb -> more prunes), and make one tile == one 64-lane batch. Zigzag now
// spans o=1..256 (8 groups) -> complete coverage for any ownt; tile id
// 0..255 still fits the 8-bit pack; init radix = exact 11th of 64. All
// gates stay conservative; insert logic untouched -> bit-identical.
// Kept: R14 radix init, R16 4-slot ring, R21 DPP insert, R22 per-query lb.

#define N_PTS    16384
#define C_FEAT   64
#define KK       11
#define NCELLS   4096                 // 16^3 Morton cells
#define TILE     64                   // sorted points per tile
#define NTILES   (N_PTS / TILE)       // 256
#define WQ       4
#define NWAVES   4
#define NTHREADS (NWAVES * 64)
#define QPB      (NWAVES * WQ)        // 16 queries per block

// d_ws layout (bytes)
#define WS_CAND  0                            // float4[2][N_PTS]   512 KB
#define WS_AABB  (WS_CAND + 2*N_PTS*16)       // float[2][NTILES][6] 12 KB
#define WS_HIST  (WS_AABB + 2*NTILES*6*4)     // int[2][NCELLS]      32 KB

__device__ __forceinline__ int cell_of(float x, float y, float z) {
    int cx = (int)floorf((x + 4.5f) * (16.0f / 9.0f));
    int cy = (int)floorf((y + 4.5f) * (16.0f / 9.0f));
    int cz = (int)floorf((z + 4.5f) * (16.0f / 9.0f));
    cx = min(15, max(0, cx));
    cy = min(15, max(0, cy));
    cz = min(15, max(0, cz));
    int m = 0;
    #pragma unroll
    for (int b = 0; b < 4; ++b)
        m |= (((cx >> b) & 1) << (3 * b)) |
             (((cy >> b) & 1) << (3 * b + 1)) |
             (((cz >> b) & 1) << (3 * b + 2));
    return m;
}

// 128 blocks x 256 thr, one point per thread. Global atomics into hist
// (pre-zeroed by hipMemsetAsync).
__global__ __launch_bounds__(256) void hist_kernel(
    const float* __restrict__ src_c, const float* __restrict__ tgt_c,
    int* __restrict__ hist)
{
    const int inst = blockIdx.x >> 6;           // 64 blocks per instance
    const float* __restrict__ coords = inst ? tgt_c : src_c;
    int* __restrict__ h = hist + inst * NCELLS;
    const int p = ((blockIdx.x & 63) << 8) + threadIdx.x;
    const float* c = coords + (size_t)p * 3;
    atomicAdd(&h[cell_of(c[0], c[1], c[2])], 1);
}

// One block per instance. Barrier scan; leaves h[cell] = exclusive base.
__global__ __launch_bounds__(1024) void scan_kernel(int* __restrict__ hist)
{
    const int inst = blockIdx.x;
    int* __restrict__ h = hist + inst * NCELLS;
    __shared__ int sd[1024];
    const int t = threadIdx.x;

    int v[4], ssum = 0;
    #pragma unroll
    for (int j = 0; j < 4; ++j) { v[j] = h[t * 4 + j]; ssum += v[j]; }
    sd[t] = ssum;
    __syncthreads();
    for (int off = 1; off < 1024; off <<= 1) {
        const int x = (t >= off) ? sd[t - off] : 0;
        __syncthreads();
        sd[t] += x;
        __syncthreads();
    }
    int base = sd[t] - ssum;
    #pragma unroll
    for (int j = 0; j < 4; ++j) { h[t * 4 + j] = base; base += v[j]; }
}

// 128 blocks x 256 thr. dst = atomicAdd(write-pointer). Within-cell order is
// nondeterministic — exactly as R8-R22 (selection proven order-independent).
__global__ __launch_bounds__(256) void scatter_kernel(
    const float* __restrict__ src_c, const float* __restrict__ tgt_c,
    int* __restrict__ hist, float4* __restrict__ cand)
{
    const int inst = blockIdx.x >> 6;
    const float* __restrict__ coords = inst ? tgt_c : src_c;
    int* __restrict__ h = hist + inst * NCELLS;
    float4* __restrict__ cb = cand + inst * N_PTS;
    const int p = ((blockIdx.x & 63) << 8) + threadIdx.x;
    const float* c = coords + (size_t)p * 3;
    const float x = c[0], y = c[1], z = c[2];
    const int dst = atomicAdd(&h[cell_of(x, y, z)], 1);
    cb[dst] = make_float4(x, y, z, __int_as_float(p));
}

// One wave per 64-pt tile: 2*NTILES blocks x 64 threads, 1 pt/lane.
__global__ void aabb_kernel(const float4* __restrict__ cand,
                            float* __restrict__ aabb) {
    const int it = blockIdx.x;                 // inst*NTILES + tile
    const int base = (it / NTILES) * N_PTS + (it % NTILES) * TILE;
    const int lane = threadIdx.x;
    const float4 a = cand[base + lane];
    float mnx = a.x, mny = a.y, mnz = a.z;
    float mxx = a.x, mxy = a.y, mxz = a.z;
    #pragma unroll
    for (int off = 1; off < 64; off <<= 1) {
        mnx = fminf(mnx, __shfl_xor(mnx, off));
        mny = fminf(mny, __shfl_xor(mny, off));
        mnz = fminf(mnz, __shfl_xor(mnz, off));
        mxx = fmaxf(mxx, __shfl_xor(mxx, off));
        mxy = fmaxf(mxy, __shfl_xor(mxy, off));
        mxz = fmaxf(mxz, __shfl_xor(mxz, off));
    }
    if (lane == 0) {
        aabb[it * 6 + 0] = mnx; aabb[it * 6 + 1] = mny; aabb[it * 6 + 2] = mnz;
        aabb[it * 6 + 3] = mxx; aabb[it * 6 + 4] = mxy; aabb[it * 6 + 5] = mxz;
    }
}

// lane lrank-1's value within the 16-lane row, 1-cycle VALU (DPP row_shr:1).
// Lanes with lrank==0 keep 'old' — callers ignore those (fst forced true).
__device__ __forceinline__ int shup16_i(int v) {
    return __builtin_amdgcn_update_dpp(v, v, 0x111, 0xf, 0xf, false);
}
__device__ __forceinline__ float shup16_f(float v) {
    return __int_as_float(
        __builtin_amdgcn_update_dpp(__float_as_int(v), __float_as_int(v),
                                    0x111, 0xf, 0xf, false));
}

// Frozen distance chain for candidate C vs query q (do not reorder).
#define DIST_TO(C, q, dout)                                                 \
  { const float csq_ = __fmaf_rn((C).z, (C).z, __fmaf_rn((C).y, (C).y,      \
                                 __fmul_rn((C).x, (C).x)));                 \
    float dot_ = __fmul_rn((C).x, qx[q]);                                   \
    dot_ = __fmaf_rn((C).y, qy[q], dot_);                                   \
    dot_ = __fmaf_rn((C).z, qz[q], dot_);                                   \
    (dout) = __fmaf_rn(dot_, -2.0f, __fadd_rn(qsq[q], csq_)); }

// One 64-candidate batch (== one tile) vs the wave's 4 queries.
// Insert chain uses DPP row_shr:1 (R21, kept).
#define PROCESS_BATCH(C)                                                    \
  {                                                                         \
    const float cx = (C).x, cy = (C).y, cz = (C).z;                         \
    const int corig = __float_as_int((C).w);                                \
    const float csq = __fmaf_rn(cz, cz, __fmaf_rn(cy, cy,                   \
                                __fmul_rn(cx, cx)));                        \
    _Pragma("unroll")                                                       \
    for (int q = 0; q < WQ; ++q) {                                          \
      float dot = __fmul_rn(cx, qx[q]);                                     \
      dot = __fmaf_rn(cy, qy[q], dot);                                      \
      dot = __fmaf_rn(cz, qz[q], dot);                                      \
      const float sum = __fadd_rn(qsq[q], csq);                             \
      const float d = __fmaf_rn(dot, -2.0f, sum);                           \
      unsigned long long m = __ballot(d <= worst[q]);                       \
      while (m) {                                                           \
        const int sl = (int)__builtin_ctzll(m);                             \
        m &= m - 1;                                                         \
        const float nd = __int_as_float(__builtin_amdgcn_readlane(          \
            __float_as_int(d), sl));                                        \
        if (nd <= worst[q]) {                                               \
          const int norig = __builtin_amdgcn_readlane(corig, sl);           \
          const float pld = shup16_f(ld);                                   \
          const int   pli = shup16_i(li);                                   \
          const bool gt = (ld > nd) || (ld == nd && li > norig);            \
          if (ingrp[q] && gt) {                                             \
            const bool pgt = (pld > nd) || (pld == nd && pli > norig);      \
            const bool fst = (lrank == 0) || (!pgt);                        \
            ld = fst ? nd : pld;                                            \
            li = fst ? norig : pli;                                         \
          }                                                                 \
          worst[q] = fminf(worst[q],                                        \
              __int_as_float(__builtin_amdgcn_readlane(                     \
                  __float_as_int(ld), q * 16 + (KK - 1))));                 \
        }                                                                   \
      }                                                                     \
    }                                                                       \
  }

#define WMAX4 fmaxf(fmaxf(worst[0], worst[1]), fmaxf(worst[2], worst[3]))

__global__ __launch_bounds__(NTHREADS) void knn_pool_kernel(
    const float* __restrict__ src_f, const float* __restrict__ tgt_f,
    const float4* __restrict__ cand, const float* __restrict__ aabb,
    float* __restrict__ out)
{
    const int inst = blockIdx.x & 1;
    const float* __restrict__ feats = inst ? tgt_f : src_f;
    float* __restrict__ outb = out + (size_t)inst * N_PTS * (2 * C_FEAT);
    const float4* __restrict__ cd = cand + inst * N_PTS;

    const int tid = threadIdx.x, wave = tid >> 6, lane = tid & 63;
    const int lq = lane >> 4, lrank = lane & 15;
    const bool inlist = (lrank < KK);

    __shared__ float sab[NTILES * 6];                 // 6 KB
    __shared__ unsigned int slist[NWAVES][NTILES];    // packed (lb|tile), 4 KB
    for (int i = tid; i < NTILES * 6; i += NTHREADS)
        sab[i] = aabb[inst * NTILES * 6 + i];
    __syncthreads();

    const int q0 = (blockIdx.x >> 1) * QPB + wave * WQ;  // sorted row
    float qx[WQ], qy[WQ], qz[WQ], qsq[WQ];
    int qor[WQ]; bool ingrp[WQ]; float worst[WQ];
    #pragma unroll
    for (int q = 0; q < WQ; ++q) {
        const float4 c = cd[q0 + q];
        qx[q] = c.x; qy[q] = c.y; qz[q] = c.z;
        qor[q] = __float_as_int(c.w);
        qsq[q] = __fmaf_rn(c.z, c.z, __fmaf_rn(c.y, c.y, __fmul_rn(c.x, c.x)));
        ingrp[q] = inlist && (lq == q);
        worst[q] = FLT_MAX;
    }

    float ld = FLT_MAX;   // lane-distributed sorted list (lex (d, orig_idx))
    int   li = 0x7fffffff;

    const int ownt = q0 / TILE;   // tile containing the queries

    // ---- own tile: radix-select exact 11th of its 64 dists -> tight init --
    {
        const float4 c0 = cd[ownt * TILE + lane];

        unsigned k0[WQ], pk[WQ];
        #pragma unroll
        for (int q = 0; q < WQ; ++q) {
            float d0;
            DIST_TO(c0, q, d0);
            const unsigned b0 = __float_as_uint(d0);
            k0[q] = b0 ^ (((unsigned)((int)b0 >> 31)) | 0x80000000u);
            pk[q] = 0u;
        }
        for (int b = 31; b >= 0; --b) {
            #pragma unroll
            for (int q = 0; q < WQ; ++q) {
                const unsigned mid = pk[q] | (1u << b);
                const int cnt = (int)__popcll(__ballot(k0[q] < mid));
                if (cnt < KK) pk[q] = mid;
            }
        }
        #pragma unroll
        for (int q = 0; q < WQ; ++q) {
            const unsigned p = pk[q];
            worst[q] = __uint_as_float(
                (p & 0x80000000u) ? (p ^ 0x80000000u) : ~p);
        }
        PROCESS_BATCH(c0);
    }

    // ---- zigzag (near->far) survivor list: PER-QUERY point-to-box lb ----
    // keep tile iff exists q: lb_q - eps <= worst[q]; entry packs
    // minlb = min_q lb_q (high 24 bits) | tile (8 bits, 0..255).
    // o = 1..256 covers all 256 tiles for any ownt (completeness).
    int nsurv = 0;
    #pragma unroll
    for (int g = 0; g < 8; ++g) {
        const int p = g * 64 + lane;
        const int o = (p >> 1) + 1;
        const int t = (p & 1) ? (ownt - o) : (ownt + o);
        bool ok = (t >= 0) && (t < NTILES);
        float mlb = 0.0f;
        if (ok) {
            const float tmnx = sab[t*6+0], tmny = sab[t*6+1], tmnz = sab[t*6+2];
            const float tmxx = sab[t*6+3], tmxy = sab[t*6+4], tmxz = sab[t*6+5];
            bool any = false;
            mlb = FLT_MAX;
            #pragma unroll
            for (int q = 0; q < WQ; ++q) {
                const float dx = fmaxf(0.f, fmaxf(tmnx - qx[q], qx[q] - tmxx));
                const float dy = fmaxf(0.f, fmaxf(tmny - qy[q], qy[q] - tmxy));
                const float dz = fmaxf(0.f, fmaxf(tmnz - qz[q], qz[q] - tmxz));
                float lb = dx * dx;
                lb = fmaf(dy, dy, lb);
                lb = fmaf(dz, dz, lb);
                any = any || ((lb - 1e-3f) <= worst[q]);
                mlb = fminf(mlb, lb);
            }
            ok = any;
        }
        const unsigned long long mk = __ballot(ok);
        if (ok) {
            const int idx = nsurv + (int)__popcll(mk & ((1ull << lane) - 1ull));
            slist[wave][idx] = (__float_as_uint(mlb) & 0xFFFFFF00u) | (unsigned)t;
        }
        nsurv += (int)__popcll(mk);
    }

    // ---- scan survivors: 4-slot prefetch ring + LIVE recheck vs wmax ----
    // One tile == one batch now. Loads for slot s issue while slot s-4 is
    // processed. Tail slots prefetch ownt harmlessly (never processed).
    float4 T0, T1, T2, T3;
    unsigned int u0 = 0, u1 = 0, u2 = 0, u3 = 0;
    {
        u0 = (0 < nsurv) ? slist[wave][0] : (unsigned)ownt;
        T0 = cd[(int)(u0 & 0xFFu) * TILE + lane];
        u1 = (1 < nsurv) ? slist[wave][1] : (unsigned)ownt;
        T1 = cd[(int)(u1 & 0xFFu) * TILE + lane];
        u2 = (2 < nsurv) ? slist[wave][2] : (unsigned)ownt;
        T2 = cd[(int)(u2 & 0xFFu) * TILE + lane];
        u3 = (3 < nsurv) ? slist[wave][3] : (unsigned)ownt;
        T3 = cd[(int)(u3 & 0xFFu) * TILE + lane];
    }
    #define SCAN_STEP(UA, TA)                                               \
      {                                                                     \
        const unsigned uN = (s + 4 < nsurv) ? slist[wave][s + 4]            \
                                            : (unsigned)ownt;               \
        const int tn = (int)(uN & 0xFFu);                                   \
        if (__uint_as_float(UA & 0xFFFFFF00u) - 1e-3f <= WMAX4) {           \
            PROCESS_BATCH(TA);                                              \
        }                                                                   \
        UA = uN;                                                            \
        TA = cd[tn * TILE + lane];                                          \
        ++s;                                                                \
      }
    int s = 0;
    while (s < nsurv) {
        SCAN_STEP(u0, T0);
        if (s >= nsurv) break;
        SCAN_STEP(u1, T1);
        if (s >= nsurv) break;
        SCAN_STEP(u2, T2);
        if (s >= nsurv) break;
        SCAN_STEP(u3, T3);
    }
    #undef SCAN_STEP

    // Rank 0 (lex-smallest: self or -1ulp near-twin) dropped positionally.
    // Ranks 1..10 -> feature columns 0..9. li holds ORIGINAL indices.
    float fv = -FLT_MAX;
    if (inlist && lrank >= 1)
        fv = feats[(size_t)li * C_FEAT + (lrank - 1)];
    #pragma unroll
    for (int off = 1; off < 16; off <<= 1)
        fv = fmaxf(fv, __shfl_xor(fv, off));

    #pragma unroll
    for (int q = 0; q < WQ; ++q) {
        const float M   = __shfl(fv, q * 16);
        const int   row = qor[q];
        const float v   = feats[(size_t)row * C_FEAT + lane];
        outb[(size_t)row * (2 * C_FEAT) + lane]          = v;
        outb[(size_t)row * (2 * C_FEAT) + C_FEAT + lane] = M - v;
    }
}

extern "C" void kernel_launch(void* const* d_in, const int* in_sizes, int n_in,
                              void* d_out, int out_size, void* d_ws, size_t ws_size,
                              hipStream_t stream) {
    const float* src_f = (const float*)d_in[0];
    const float* tgt_f = (const float*)d_in[1];
    const float* src_c = (const float*)d_in[2];
    const float* tgt_c = (const float*)d_in[3];
    float* out = (float*)d_out;

    char* ws = (char*)d_ws;
    float4* cand = (float4*)(ws + WS_CAND);
    float*  aabb = (float*) (ws + WS_AABB);
    int*    hist = (int*)   (ws + WS_HIST);

    hipMemsetAsync(hist, 0, 2 * NCELLS * sizeof(int), stream);
    hipLaunchKernelGGL(hist_kernel, dim3(128), dim3(256), 0, stream,
                       src_c, tgt_c, hist);
    hipLaunchKernelGGL(scan_kernel, dim3(2), dim3(1024), 0, stream, hist);
    hipLaunchKernelGGL(scatter_kernel, dim3(128), dim3(256), 0, stream,
                       src_c, tgt_c, hist, cand);
    hipLaunchKernelGGL(aabb_kernel, dim3(2 * NTILES), dim3(64), 0, stream,
                       cand, aabb);
    hipLaunchKernelGGL(knn_pool_kernel, dim3(2 * (N_PTS / QPB)), dim3(NTHREADS),
                       0, stream, src_f, tgt_f, cand, aabb, out);
}

// Round 14
// 184.728 us; speedup vs baseline: 1.1615x; 1.1615x over previous
//
#include <hip/hip_runtime.h>
#include <cfloat>
#include <math.h>

// Exact-replication KNN (k=10, +self) + rank-column gather max-pool.
// NUMERICS FROZEN (R3 pass, absmax 0.0): fp32 chains
//   sq  = fma(z,z, fma(y,y, rn(x*x)))
//   dot = fma(z,z', fma(y,y', rn(x*x')))
//   d   = fma(dot, -2, rn(sq_i+sq_j))    [== rn(sum - rn(2*dot)), 2*dot exact]
// Selection order = jax top_k = ascending lexicographic (d, orig_idx) —
// proven order-independent in R8/R9 (absmax 0.0, nondeterministic scatter).
//
// Round 24: R23 (TILE=64) regressed (138us: 2x per-tile overhead, no extra
// pruning) -> reverted to R22 (TILE=128, best wall 189.1). New: PER-TILE
// RADIX PRE-GATE. R14's arithmetic: one serial while(m) iteration ~ 320cy
// (readlane chains). Tail waves (sparse regions) start with a loose worst
// -> early scan tiles give 20-50 mask bits each -> hundreds of serial
// iterations = the 113us tail. Now if popc(m) > 13, radix-select (32
// ballot steps, wave-parallel, ~250cy — R14's proven machinery) the EXACT
// 11th of this tile's 64 candidate distances, set worst = min(worst,
// tile11), recompute m (<= ~11+ties bits). Exact: min(worst,tile11) >=
// 11th-of(list u tile) >= final 11th, so excluded candidates cannot be in
// the union top-11; the unchanged insert loop rebuilds the exact lex list
// (same argument as R14 init gate). Light tiles: 2-inst uniform test.
// Kept: R14 radix init, R16 4-slot ring, R21 DPP insert, R22 per-query lb.

#define N_PTS    16384
#define C_FEAT   64
#define KK       11
#define NCELLS   4096                 // 16^3 Morton cells
#define TILE     128                  // sorted points per tile
#define NTILES   (N_PTS / TILE)       // 128
#define WQ       4
#define NWAVES   4
#define NTHREADS (NWAVES * 64)
#define QPB      (NWAVES * WQ)        // 16 queries per block
#define HEAVY    13                   // mask-bits threshold for pre-gate

// d_ws layout (bytes)
#define WS_CAND  0                            // float4[2][N_PTS]   512 KB
#define WS_AABB  (WS_CAND + 2*N_PTS*16)       // float[2][NTILES][6]  6 KB
#define WS_HIST  (WS_AABB + 2*NTILES*6*4)     // int[2][NCELLS]      32 KB

__device__ __forceinline__ int cell_of(float x, float y, float z) {
    int cx = (int)floorf((x + 4.5f) * (16.0f / 9.0f));
    int cy = (int)floorf((y + 4.5f) * (16.0f / 9.0f));
    int cz = (int)floorf((z + 4.5f) * (16.0f / 9.0f));
    cx = min(15, max(0, cx));
    cy = min(15, max(0, cy));
    cz = min(15, max(0, cz));
    int m = 0;
    #pragma unroll
    for (int b = 0; b < 4; ++b)
        m |= (((cx >> b) & 1) << (3 * b)) |
             (((cy >> b) & 1) << (3 * b + 1)) |
             (((cz >> b) & 1) << (3 * b + 2));
    return m;
}

// 128 blocks x 256 thr, one point per thread. Global atomics into hist
// (pre-zeroed by hipMemsetAsync).
__global__ __launch_bounds__(256) void hist_kernel(
    const float* __restrict__ src_c, const float* __restrict__ tgt_c,
    int* __restrict__ hist)
{
    const int inst = blockIdx.x >> 6;           // 64 blocks per instance
    const float* __restrict__ coords = inst ? tgt_c : src_c;
    int* __restrict__ h = hist + inst * NCELLS;
    const int p = ((blockIdx.x & 63) << 8) + threadIdx.x;
    const float* c = coords + (size_t)p * 3;
    atomicAdd(&h[cell_of(c[0], c[1], c[2])], 1);
}

// One block per instance. Barrier scan; leaves h[cell] = exclusive base.
__global__ __launch_bounds__(1024) void scan_kernel(int* __restrict__ hist)
{
    const int inst = blockIdx.x;
    int* __restrict__ h = hist + inst * NCELLS;
    __shared__ int sd[1024];
    const int t = threadIdx.x;

    int v[4], ssum = 0;
    #pragma unroll
    for (int j = 0; j < 4; ++j) { v[j] = h[t * 4 + j]; ssum += v[j]; }
    sd[t] = ssum;
    __syncthreads();
    for (int off = 1; off < 1024; off <<= 1) {
        const int x = (t >= off) ? sd[t - off] : 0;
        __syncthreads();
        sd[t] += x;
        __syncthreads();
    }
    int base = sd[t] - ssum;
    #pragma unroll
    for (int j = 0; j < 4; ++j) { h[t * 4 + j] = base; base += v[j]; }
}

// 128 blocks x 256 thr. dst = atomicAdd(write-pointer). Within-cell order is
// nondeterministic — exactly as R8-R23 (selection proven order-independent).
__global__ __launch_bounds__(256) void scatter_kernel(
    const float* __restrict__ src_c, const float* __restrict__ tgt_c,
    int* __restrict__ hist, float4* __restrict__ cand)
{
    const int inst = blockIdx.x >> 6;
    const float* __restrict__ coords = inst ? tgt_c : src_c;
    int* __restrict__ h = hist + inst * NCELLS;
    float4* __restrict__ cb = cand + inst * N_PTS;
    const int p = ((blockIdx.x & 63) << 8) + threadIdx.x;
    const float* c = coords + (size_t)p * 3;
    const float x = c[0], y = c[1], z = c[2];
    const int dst = atomicAdd(&h[cell_of(x, y, z)], 1);
    cb[dst] = make_float4(x, y, z, __int_as_float(p));
}

__global__ void aabb_kernel(const float4* __restrict__ cand,
                            float* __restrict__ aabb) {
    const int it = blockIdx.x;                 // inst*NTILES + tile
    const int base = (it / NTILES) * N_PTS + (it % NTILES) * TILE;
    const int lane = threadIdx.x;              // 64 threads, 2 pts each
    float4 a = cand[base + lane], b = cand[base + 64 + lane];
    float mnx = fminf(a.x, b.x), mny = fminf(a.y, b.y), mnz = fminf(a.z, b.z);
    float mxx = fmaxf(a.x, b.x), mxy = fmaxf(a.y, b.y), mxz = fmaxf(a.z, b.z);
    #pragma unroll
    for (int off = 1; off < 64; off <<= 1) {
        mnx = fminf(mnx, __shfl_xor(mnx, off));
        mny = fminf(mny, __shfl_xor(mny, off));
        mnz = fminf(mnz, __shfl_xor(mnz, off));
        mxx = fmaxf(mxx, __shfl_xor(mxx, off));
        mxy = fmaxf(mxy, __shfl_xor(mxy, off));
        mxz = fmaxf(mxz, __shfl_xor(mxz, off));
    }
    if (lane == 0) {
        aabb[it * 6 + 0] = mnx; aabb[it * 6 + 1] = mny; aabb[it * 6 + 2] = mnz;
        aabb[it * 6 + 3] = mxx; aabb[it * 6 + 4] = mxy; aabb[it * 6 + 5] = mxz;
    }
}

// lane lrank-1's value within the 16-lane row, 1-cycle VALU (DPP row_shr:1).
// Lanes with lrank==0 keep 'old' — callers ignore those (fst forced true).
__device__ __forceinline__ int shup16_i(int v) {
    return __builtin_amdgcn_update_dpp(v, v, 0x111, 0xf, 0xf, false);
}
__device__ __forceinline__ float shup16_f(float v) {
    return __int_as_float(
        __builtin_amdgcn_update_dpp(__float_as_int(v), __float_as_int(v),
                                    0x111, 0xf, 0xf, false));
}

// Frozen distance chain for candidate C vs query q (do not reorder).
#define DIST_TO(C, q, dout)                                                 \
  { const float csq_ = __fmaf_rn((C).z, (C).z, __fmaf_rn((C).y, (C).y,      \
                                 __fmul_rn((C).x, (C).x)));                 \
    float dot_ = __fmul_rn((C).x, qx[q]);                                   \
    dot_ = __fmaf_rn((C).y, qy[q], dot_);                                   \
    dot_ = __fmaf_rn((C).z, qz[q], dot_);                                   \
    (dout) = __fmaf_rn(dot_, -2.0f, __fadd_rn(qsq[q], csq_)); }

// One 64-candidate batch vs the wave's 4 queries (proven in R8/R9).
// DPP insert chain (R21). NEW: heavy-mask radix pre-gate — when popc(m) >
// HEAVY, tighten worst[q] to min(worst, exact tile-11th) before the serial
// loop; admitted set still contains the union top-11 -> list bit-identical.
#define PROCESS_BATCH(C)                                                    \
  {                                                                         \
    const float cx = (C).x, cy = (C).y, cz = (C).z;                         \
    const int corig = __float_as_int((C).w);                                \
    const float csq = __fmaf_rn(cz, cz, __fmaf_rn(cy, cy,                   \
                                __fmul_rn(cx, cx)));                        \
    _Pragma("unroll")                                                       \
    for (int q = 0; q < WQ; ++q) {                                          \
      float dot = __fmul_rn(cx, qx[q]);                                     \
      dot = __fmaf_rn(cy, qy[q], dot);                                      \
      dot = __fmaf_rn(cz, qz[q], dot);                                      \
      const float sum = __fadd_rn(qsq[q], csq);                             \
      const float d = __fmaf_rn(dot, -2.0f, sum);                           \
      unsigned long long m = __ballot(d <= worst[q]);                       \
      if ((int)__popcll(m) > HEAVY) {                                       \
        const unsigned bd_ = __float_as_uint(d);                            \
        const unsigned kd_ = bd_ ^ (((unsigned)((int)bd_ >> 31))            \
                                    | 0x80000000u);                         \
        unsigned pk_ = 0u;                                                  \
        for (int b_ = 31; b_ >= 0; --b_) {                                  \
          const unsigned mid_ = pk_ | (1u << b_);                           \
          if ((int)__popcll(__ballot(kd_ < mid_)) < KK) pk_ = mid_;         \
        }                                                                   \
        const float t11_ = __uint_as_float(                                 \
            (pk_ & 0x80000000u) ? (pk_ ^ 0x80000000u) : ~pk_);              \
        worst[q] = fminf(worst[q], t11_);                                   \
        m = __ballot(d <= worst[q]);                                        \
      }                                                                     \
      while (m) {                                                           \
        const int sl = (int)__builtin_ctzll(m);                             \
        m &= m - 1;                                                         \
        const float nd = __int_as_float(__builtin_amdgcn_readlane(          \
            __float_as_int(d), sl));                                        \
        if (nd <= worst[q]) {                                               \
          const int norig = __builtin_amdgcn_readlane(corig, sl);           \
          const float pld = shup16_f(ld);                                   \
          const int   pli = shup16_i(li);                                   \
          const bool gt = (ld > nd) || (ld == nd && li > norig);            \
          if (ingrp[q] && gt) {                                             \
            const bool pgt = (pld > nd) || (pld == nd && pli > norig);      \
            const bool fst = (lrank == 0) || (!pgt);                        \
            ld = fst ? nd : pld;                                            \
            li = fst ? norig : pli;                                         \
          }                                                                 \
          worst[q] = fminf(worst[q],                                        \
              __int_as_float(__builtin_amdgcn_readlane(                     \
                  __float_as_int(ld), q * 16 + (KK - 1))));                 \
        }                                                                   \
      }                                                                     \
    }                                                                       \
  }

#define WMAX4 fmaxf(fmaxf(worst[0], worst[1]), fmaxf(worst[2], worst[3]))

__global__ __launch_bounds__(NTHREADS) void knn_pool_kernel(
    const float* __restrict__ src_f, const float* __restrict__ tgt_f,
    const float4* __restrict__ cand, const float* __restrict__ aabb,
    float* __restrict__ out)
{
    const int inst = blockIdx.x & 1;
    const float* __restrict__ feats = inst ? tgt_f : src_f;
    float* __restrict__ outb = out + (size_t)inst * N_PTS * (2 * C_FEAT);
    const float4* __restrict__ cd = cand + inst * N_PTS;

    const int tid = threadIdx.x, wave = tid >> 6, lane = tid & 63;
    const int lq = lane >> 4, lrank = lane & 15;
    const bool inlist = (lrank < KK);

    __shared__ float sab[NTILES * 6];                 // 3 KB
    __shared__ unsigned int slist[NWAVES][NTILES];    // packed (lb|tile), 2 KB
    for (int i = tid; i < NTILES * 6; i += NTHREADS)
        sab[i] = aabb[inst * NTILES * 6 + i];
    __syncthreads();

    const int q0 = (blockIdx.x >> 1) * QPB + wave * WQ;  // sorted row
    float qx[WQ], qy[WQ], qz[WQ], qsq[WQ];
    int qor[WQ]; bool ingrp[WQ]; float worst[WQ];
    #pragma unroll
    for (int q = 0; q < WQ; ++q) {
        const float4 c = cd[q0 + q];
        qx[q] = c.x; qy[q] = c.y; qz[q] = c.z;
        qor[q] = __float_as_int(c.w);
        qsq[q] = __fmaf_rn(c.z, c.z, __fmaf_rn(c.y, c.y, __fmul_rn(c.x, c.x)));
        ingrp[q] = inlist && (lq == q);
        worst[q] = FLT_MAX;
    }

    float ld = FLT_MAX;   // lane-distributed sorted list (lex (d, orig_idx))
    int   li = 0x7fffffff;

    const int ownt = q0 / TILE;   // tile containing the queries

    // ---- own tile: radix-select exact 11th distance -> tight worst init --
    {
        const float4 c0 = cd[ownt * TILE + lane];
        const float4 c1 = cd[ownt * TILE + 64 + lane];

        // Order-preserving uint keys of the frozen fp32 distances
        // (bijective; handles the -eps self-distance sign case).
        unsigned k0[WQ], k1[WQ], pk[WQ];
        #pragma unroll
        for (int q = 0; q < WQ; ++q) {
            float d0, d1;
            DIST_TO(c0, q, d0);
            DIST_TO(c1, q, d1);
            const unsigned b0 = __float_as_uint(d0), b1 = __float_as_uint(d1);
            k0[q] = b0 ^ (((unsigned)((int)b0 >> 31)) | 0x80000000u);
            k1[q] = b1 ^ (((unsigned)((int)b1 >> 31)) | 0x80000000u);
            pk[q] = 0u;
        }
        // MSB->LSB bisection: after the loop pk[q] == key of the exact
        // 11th-smallest (counting multiplicity) of the 128 own-tile dists.
        for (int b = 31; b >= 0; --b) {
            #pragma unroll
            for (int q = 0; q < WQ; ++q) {
                const unsigned mid = pk[q] | (1u << b);
                const int cnt = (int)__popcll(__ballot(k0[q] < mid))
                              + (int)__popcll(__ballot(k1[q] < mid));
                if (cnt < KK) pk[q] = mid;
            }
        }
        #pragma unroll
        for (int q = 0; q < WQ; ++q) {
            const unsigned p = pk[q];
            worst[q] = __uint_as_float(
                (p & 0x80000000u) ? (p ^ 0x80000000u) : ~p);
        }
        // Gated batches: m now has ~11+ties bits total; the serial insert
        // (unchanged logic) rebuilds the exact lex-sorted list.
        PROCESS_BATCH(c0);
        PROCESS_BATCH(c1);
    }

    // ---- zigzag (near->far) survivor list: PER-QUERY point-to-box lb ----
    // keep tile iff exists q: lb_q - eps <= worst[q] (worst = exact own-tile
    // 11th; final worst only shrinks -> skip is safe). Entry packs
    // minlb = min_q lb_q: (bits & ~0xFF) | tile — minlb>=0 so uint order ==
    // lb order; unpacked value rounds DOWN => recheck stays conservative.
    int nsurv = 0;
    #pragma unroll
    for (int g = 0; g < 4; ++g) {
        const int p = g * 64 + lane;
        const int o = (p >> 1) + 1;
        const int t = (p & 1) ? (ownt - o) : (ownt + o);
        bool ok = (t >= 0) && (t < NTILES);
        float mlb = 0.0f;
        if (ok) {
            const float tmnx = sab[t*6+0], tmny = sab[t*6+1], tmnz = sab[t*6+2];
            const float tmxx = sab[t*6+3], tmxy = sab[t*6+4], tmxz = sab[t*6+5];
            bool any = false;
            mlb = FLT_MAX;
            #pragma unroll
            for (int q = 0; q < WQ; ++q) {
                const float dx = fmaxf(0.f, fmaxf(tmnx - qx[q], qx[q] - tmxx));
                const float dy = fmaxf(0.f, fmaxf(tmny - qy[q], qy[q] - tmxy));
                const float dz = fmaxf(0.f, fmaxf(tmnz - qz[q], qz[q] - tmxz));
                float lb = dx * dx;
                lb = fmaf(dy, dy, lb);
                lb = fmaf(dz, dz, lb);
                any = any || ((lb - 1e-3f) <= worst[q]);
                mlb = fminf(mlb, lb);
            }
            ok = any;
        }
        const unsigned long long mk = __ballot(ok);
        if (ok) {
            const int idx = nsurv + (int)__popcll(mk & ((1ull << lane) - 1ull));
            slist[wave][idx] = (__float_as_uint(mlb) & 0xFFFFFF00u) | (unsigned)t;
        }
        nsurv += (int)__popcll(mk);
    }

    // ---- scan survivors: 4-slot prefetch ring + LIVE recheck vs wmax ----
    // Loads for slot s issue while slot s-4 is processed (~3 tiles of
    // latency cover for the occupancy-decayed tail regime). Tail slots
    // prefetch ownt harmlessly (never processed: loop bound).
    float4 T0a, T0b, T1a, T1b, T2a, T2b, T3a, T3b;
    unsigned int u0 = 0, u1 = 0, u2 = 0, u3 = 0;
    {
        u0 = (0 < nsurv) ? slist[wave][0] : (unsigned)ownt;
        const int t0 = (int)(u0 & 0xFFu);
        T0a = cd[t0 * TILE + lane]; T0b = cd[t0 * TILE + 64 + lane];
        u1 = (1 < nsurv) ? slist[wave][1] : (unsigned)ownt;
        const int t1 = (int)(u1 & 0xFFu);
        T1a = cd[t1 * TILE + lane]; T1b = cd[t1 * TILE + 64 + lane];
        u2 = (2 < nsurv) ? slist[wave][2] : (unsigned)ownt;
        const int t2 = (int)(u2 & 0xFFu);
        T2a = cd[t2 * TILE + lane]; T2b = cd[t2 * TILE + 64 + lane];
        u3 = (3 < nsurv) ? slist[wave][3] : (unsigned)ownt;
        const int t3 = (int)(u3 & 0xFFu);
        T3a = cd[t3 * TILE + lane]; T3b = cd[t3 * TILE + 64 + lane];
    }
    #define SCAN_STEP(UA, TA, TB)                                           \
      {                                                                     \
        const unsigned uN = (s + 4 < nsurv) ? slist[wave][s + 4]            \
                                            : (unsigned)ownt;               \
        const int tn = (int)(uN & 0xFFu);                                   \
        if (__uint_as_float(UA & 0xFFFFFF00u) - 1e-3f <= WMAX4) {           \
            PROCESS_BATCH(TA);                                              \
            PROCESS_BATCH(TB);                                              \
        }                                                                   \
        UA = uN;                                                            \
        TA = cd[tn * TILE + lane]; TB = cd[tn * TILE + 64 + lane];          \
        ++s;                                                                \
      }
    int s = 0;
    while (s < nsurv) {
        SCAN_STEP(u0, T0a, T0b);
        if (s >= nsurv) break;
        SCAN_STEP(u1, T1a, T1b);
        if (s >= nsurv) break;
        SCAN_STEP(u2, T2a, T2b);
        if (s >= nsurv) break;
        SCAN_STEP(u3, T3a, T3b);
    }
    #undef SCAN_STEP

    // Rank 0 (lex-smallest: self or -1ulp near-twin) dropped positionally.
    // Ranks 1..10 -> feature columns 0..9. li holds ORIGINAL indices.
    float fv = -FLT_MAX;
    if (inlist && lrank >= 1)
        fv = feats[(size_t)li * C_FEAT + (lrank - 1)];
    #pragma unroll
    for (int off = 1; off < 16; off <<= 1)
        fv = fmaxf(fv, __shfl_xor(fv, off));

    #pragma unroll
    for (int q = 0; q < WQ; ++q) {
        const float M   = __shfl(fv, q * 16);
        const int   row = qor[q];
        const float v   = feats[(size_t)row * C_FEAT + lane];
        outb[(size_t)row * (2 * C_FEAT) + lane]          = v;
        outb[(size_t)row * (2 * C_FEAT) + C_FEAT + lane] = M - v;
    }
}

extern "C" void kernel_launch(void* const* d_in, const int* in_sizes, int n_in,
                              void* d_out, int out_size, void* d_ws, size_t ws_size,
                              hipStream_t stream) {
    const float* src_f = (const float*)d_in[0];
    const float* tgt_f = (const float*)d_in[1];
    const float* src_c = (const float*)d_in[2];
    const float* tgt_c = (const float*)d_in[3];
    float* out = (float*)d_out;

    char* ws = (char*)d_ws;
    float4* cand = (float4*)(ws + WS_CAND);
    float*  aabb = (float*) (ws + WS_AABB);
    int*    hist = (int*)   (ws + WS_HIST);

    hipMemsetAsync(hist, 0, 2 * NCELLS * sizeof(int), stream);
    hipLaunchKernelGGL(hist_kernel, dim3(128), dim3(256), 0, stream,
                       src_c, tgt_c, hist);
    hipLaunchKernelGGL(scan_kernel, dim3(2), dim3(1024), 0, stream, hist);
    hipLaunchKernelGGL(scatter_kernel, dim3(128), dim3(256), 0, stream,
                       src_c, tgt_c, hist, cand);
    hipLaunchKernelGGL(aabb_kernel, dim3(2 * NTILES), dim3(64), 0, stream,
                       cand, aabb);
    hipLaunchKernelGGL(knn_pool_kernel, dim3(2 * (N_PTS / QPB)), dim3(NTHREADS),
                       0, stream, src_f, tgt_f, cand, aabb, out);
}

// Round 15
// 176.378 us; speedup vs baseline: 1.2164x; 1.0473x over previous
//
#include <hip/hip_runtime.h>
#include <cfloat>
#include <math.h>

// Exact-replication KNN (k=10, +self) + rank-column gather max-pool.
// NUMERICS FROZEN (R3 pass, absmax 0.0): fp32 chains
//   sq  = fma(z,z, fma(y,y, rn(x*x)))
//   dot = fma(z,z', fma(y,y', rn(x*x')))
//   d   = fma(dot, -2, rn(sq_i+sq_j))    [== rn(sum - rn(2*dot)), 2*dot exact]
// Selection order = jax top_k = ascending lexicographic (d, orig_idx) —
// proven order-independent in R8/R9 (absmax 0.0, nondeterministic scatter).
//
// Round 25: NO SERIAL INSERTS. R24 proved (a) serial insert iterations
// (~320cy each) are the tail cost and (b) wave-parallel radix-select can
// replace them. Insight: the scan only needs W[q] = running 11th bound;
// the sorted list is needed only at the END. New scan path: dist -> ballot
// vs W -> heavy radix pre-gate (R24) -> PARALLEL APPEND of (d,idx) to a
// per-wave-per-query LDS queue (ballot-prefix offsets, no atomics, wave-
// local). W tightens via radix only: per-tile 11ths, and queue COMPACTION
// (radix queue-11th == exact running 11th since queue holds all candidates
// <= any past W >= running 11th; filter+prefix-compact). Final per query:
// compact (exact final 11th) -> 64-lane bitonic sort on lex (d,idx) (21
// shfl stages) -> ranks 1..10 gather (identical tie semantics to the old
// insert; rank 0 dropped positionally). All gates >= final 11th at all
// times -> exact, bit-identical selection. Unlike R20: same QPB=16 block
// decomposition (L2-proven), wave-local queues, no fallback path.
// Kept: R14 init radix, R16 4-slot ring, R22 per-query lb, R24 pre-gate.
// (Theoretical cap: >21 exact fp32-distance ties at the 11th could drop
// a tie candidate at QCAP guard — measure-zero for continuous coords.)

#define N_PTS    16384
#define C_FEAT   64
#define KK       11
#define NCELLS   4096                 // 16^3 Morton cells
#define TILE     128                  // sorted points per tile
#define NTILES   (N_PTS / TILE)       // 128
#define WQ       4
#define NWAVES   4
#define NTHREADS (NWAVES * 64)
#define QPB      (NWAVES * WQ)        // 16 queries per block
#define HEAVY    13                   // mask-bits threshold for pre-gate
#define QCAP     96                   // queue slots per query

// d_ws layout (bytes)
#define WS_CAND  0                            // float4[2][N_PTS]   512 KB
#define WS_AABB  (WS_CAND + 2*N_PTS*16)       // float[2][NTILES][6]  6 KB
#define WS_HIST  (WS_AABB + 2*NTILES*6*4)     // int[2][NCELLS]      32 KB

__device__ __forceinline__ int cell_of(float x, float y, float z) {
    int cx = (int)floorf((x + 4.5f) * (16.0f / 9.0f));
    int cy = (int)floorf((y + 4.5f) * (16.0f / 9.0f));
    int cz = (int)floorf((z + 4.5f) * (16.0f / 9.0f));
    cx = min(15, max(0, cx));
    cy = min(15, max(0, cy));
    cz = min(15, max(0, cz));
    int m = 0;
    #pragma unroll
    for (int b = 0; b < 4; ++b)
        m |= (((cx >> b) & 1) << (3 * b)) |
             (((cy >> b) & 1) << (3 * b + 1)) |
             (((cz >> b) & 1) << (3 * b + 2));
    return m;
}

// Monotone (order-preserving, bijective) float<->uint key.
__device__ __forceinline__ unsigned keyf(float f) {
    const unsigned u = __float_as_uint(f);
    return (u & 0x80000000u) ? ~u : (u | 0x80000000u);
}
__device__ __forceinline__ float unkeyf(unsigned k) {
    return __uint_as_float((k & 0x80000000u) ? (k ^ 0x80000000u) : ~k);
}

// 128 blocks x 256 thr, one point per thread. Global atomics into hist
// (pre-zeroed by hipMemsetAsync).
__global__ __launch_bounds__(256) void hist_kernel(
    const float* __restrict__ src_c, const float* __restrict__ tgt_c,
    int* __restrict__ hist)
{
    const int inst = blockIdx.x >> 6;           // 64 blocks per instance
    const float* __restrict__ coords = inst ? tgt_c : src_c;
    int* __restrict__ h = hist + inst * NCELLS;
    const int p = ((blockIdx.x & 63) << 8) + threadIdx.x;
    const float* c = coords + (size_t)p * 3;
    atomicAdd(&h[cell_of(c[0], c[1], c[2])], 1);
}

// One block per instance. Barrier scan; leaves h[cell] = exclusive base.
__global__ __launch_bounds__(1024) void scan_kernel(int* __restrict__ hist)
{
    const int inst = blockIdx.x;
    int* __restrict__ h = hist + inst * NCELLS;
    __shared__ int sd[1024];
    const int t = threadIdx.x;

    int v[4], ssum = 0;
    #pragma unroll
    for (int j = 0; j < 4; ++j) { v[j] = h[t * 4 + j]; ssum += v[j]; }
    sd[t] = ssum;
    __syncthreads();
    for (int off = 1; off < 1024; off <<= 1) {
        const int x = (t >= off) ? sd[t - off] : 0;
        __syncthreads();
        sd[t] += x;
        __syncthreads();
    }
    int base = sd[t] - ssum;
    #pragma unroll
    for (int j = 0; j < 4; ++j) { h[t * 4 + j] = base; base += v[j]; }
}

// 128 blocks x 256 thr. dst = atomicAdd(write-pointer). Within-cell order is
// nondeterministic — exactly as R8-R24 (selection proven order-independent).
__global__ __launch_bounds__(256) void scatter_kernel(
    const float* __restrict__ src_c, const float* __restrict__ tgt_c,
    int* __restrict__ hist, float4* __restrict__ cand)
{
    const int inst = blockIdx.x >> 6;
    const float* __restrict__ coords = inst ? tgt_c : src_c;
    int* __restrict__ h = hist + inst * NCELLS;
    float4* __restrict__ cb = cand + inst * N_PTS;
    const int p = ((blockIdx.x & 63) << 8) + threadIdx.x;
    const float* c = coords + (size_t)p * 3;
    const float x = c[0], y = c[1], z = c[2];
    const int dst = atomicAdd(&h[cell_of(x, y, z)], 1);
    cb[dst] = make_float4(x, y, z, __int_as_float(p));
}

__global__ void aabb_kernel(const float4* __restrict__ cand,
                            float* __restrict__ aabb) {
    const int it = blockIdx.x;                 // inst*NTILES + tile
    const int base = (it / NTILES) * N_PTS + (it % NTILES) * TILE;
    const int lane = threadIdx.x;              // 64 threads, 2 pts each
    float4 a = cand[base + lane], b = cand[base + 64 + lane];
    float mnx = fminf(a.x, b.x), mny = fminf(a.y, b.y), mnz = fminf(a.z, b.z);
    float mxx = fmaxf(a.x, b.x), mxy = fmaxf(a.y, b.y), mxz = fmaxf(a.z, b.z);
    #pragma unroll
    for (int off = 1; off < 64; off <<= 1) {
        mnx = fminf(mnx, __shfl_xor(mnx, off));
        mny = fminf(mny, __shfl_xor(mny, off));
        mnz = fminf(mnz, __shfl_xor(mnz, off));
        mxx = fmaxf(mxx, __shfl_xor(mxx, off));
        mxy = fmaxf(mxy, __shfl_xor(mxy, off));
        mxz = fmaxf(mxz, __shfl_xor(mxz, off));
    }
    if (lane == 0) {
        aabb[it * 6 + 0] = mnx; aabb[it * 6 + 1] = mny; aabb[it * 6 + 2] = mnz;
        aabb[it * 6 + 3] = mxx; aabb[it * 6 + 4] = mxy; aabb[it * 6 + 5] = mxz;
    }
}

// Frozen distance chain for candidate C vs query q (do not reorder).
#define DIST_TO(C, q, dout)                                                 \
  { const float csq_ = __fmaf_rn((C).z, (C).z, __fmaf_rn((C).y, (C).y,      \
                                 __fmul_rn((C).x, (C).x)));                 \
    float dot_ = __fmul_rn((C).x, qx[q]);                                   \
    dot_ = __fmaf_rn((C).y, qy[q], dot_);                                   \
    dot_ = __fmaf_rn((C).z, qz[q], dot_);                                   \
    (dout) = __fmaf_rn(dot_, -2.0f, __fadd_rn(qsq[q], csq_)); }

#define LMASK_LT ((1ull << lane) - 1ull)

// Exact 11th-smallest key of 64 wave-held keys (ballot bisection).
#define RADIX11_1(KD, PKOUT)                                                \
  { unsigned pkr_ = 0u;                                                     \
    for (int b_ = 31; b_ >= 0; --b_) {                                      \
      const unsigned mid_ = pkr_ | (1u << b_);                              \
      if ((int)__popcll(__ballot((KD) < mid_)) < KK) pkr_ = mid_;           \
    }                                                                       \
    (PKOUT) = pkr_; }

// Exact 11th-smallest key of 128 wave-held keys (two regs).
#define RADIX11_2(K0, K1, PKOUT)                                            \
  { unsigned pkr_ = 0u;                                                     \
    for (int b_ = 31; b_ >= 0; --b_) {                                      \
      const unsigned mid_ = pkr_ | (1u << b_);                              \
      const int c_ = (int)__popcll(__ballot((K0) < mid_))                   \
                   + (int)__popcll(__ballot((K1) < mid_));                  \
      if (c_ < KK) pkr_ = mid_;                                             \
    }                                                                       \
    (PKOUT) = pkr_; }

// Compact query q's queue to entries <= its exact 11th; W[q] becomes the
// EXACT running 11th (queue holds all candidates <= every past W >= running
// 11th, so the 11 smallest seen are all present). Wave-local, no atomics.
// Same-wave ds read->write ordering is in-order (proven assumption R10+).
#define COMPACT(q)                                                          \
  { const int cc_ = cnt[q];                                                 \
    const int l1_ = 64 + lane;                                              \
    const float cd0_ = (lane < cc_) ? qds[wave][q][lane] : FLT_MAX;         \
    const int   ci0_ = (lane < cc_) ? qis[wave][q][lane] : 0x7fffffff;      \
    const float cd1_ = (l1_ < cc_) ? qds[wave][q][l1_] : FLT_MAX;           \
    const int   ci1_ = (l1_ < cc_) ? qis[wave][q][l1_] : 0x7fffffff;        \
    const unsigned ck0_ = keyf(cd0_), ck1_ = keyf(cd1_);                    \
    unsigned pk_;                                                           \
    RADIX11_2(ck0_, ck1_, pk_);                                             \
    W[q] = unkeyf(pk_);                                                     \
    const bool f0_ = (ck0_ <= pk_) && (lane < cc_);                         \
    const bool f1_ = (ck1_ <= pk_) && (l1_ < cc_);                          \
    const unsigned long long b0_ = __ballot(f0_), b1_ = __ballot(f1_);      \
    const int n0_ = (int)__popcll(b0_);                                     \
    if (f0_) { const int o_ = (int)__popcll(b0_ & LMASK_LT);                \
               qds[wave][q][o_] = cd0_; qis[wave][q][o_] = ci0_; }          \
    if (f1_) { const int o_ = n0_ + (int)__popcll(b1_ & LMASK_LT);          \
               qds[wave][q][o_] = cd1_; qis[wave][q][o_] = ci1_; }          \
    cnt[q] = n0_ + (int)__popcll(b1_); }

// One 64-candidate batch vs the wave's 4 queries: dist -> gate -> heavy
// radix pre-gate (R24) -> capacity compact -> parallel prefix append.
// No serial per-candidate loop anywhere.
#define APPEND_BATCH(C)                                                     \
  {                                                                         \
    const float cx = (C).x, cy = (C).y, cz = (C).z;                         \
    const int corig = __float_as_int((C).w);                                \
    const float csq = __fmaf_rn(cz, cz, __fmaf_rn(cy, cy,                   \
                                __fmul_rn(cx, cx)));                        \
    _Pragma("unroll")                                                       \
    for (int q = 0; q < WQ; ++q) {                                          \
      float dot = __fmul_rn(cx, qx[q]);                                     \
      dot = __fmaf_rn(cy, qy[q], dot);                                      \
      dot = __fmaf_rn(cz, qz[q], dot);                                      \
      const float sum = __fadd_rn(qsq[q], csq);                             \
      const float d = __fmaf_rn(dot, -2.0f, sum);                           \
      unsigned long long m = __ballot(d <= W[q]);                           \
      if (m) {                                                              \
        if ((int)__popcll(m) > HEAVY) {                                     \
          const unsigned kd_ = keyf(d);                                     \
          unsigned pk_;                                                     \
          RADIX11_1(kd_, pk_);                                              \
          W[q] = fminf(W[q], unkeyf(pk_));                                  \
          m = __ballot(d <= W[q]);                                          \
        }                                                                   \
        if (cnt[q] + (int)__popcll(m) > QCAP) {                             \
          COMPACT(q);                                                       \
          m = __ballot(d <= W[q]);                                          \
        }                                                                   \
        const int base_ = cnt[q];                                           \
        const int o_ = base_ + (int)__popcll(m & LMASK_LT);                 \
        if (((m >> lane) & 1ull) && o_ < QCAP) {                            \
          qds[wave][q][o_] = d; qis[wave][q][o_] = corig;                   \
        }                                                                   \
        cnt[q] = min(base_ + (int)__popcll(m), QCAP);                       \
      }                                                                     \
    }                                                                       \
  }

#define WMAX4 fmaxf(fmaxf(W[0], W[1]), fmaxf(W[2], W[3]))

__global__ __launch_bounds__(NTHREADS) void knn_pool_kernel(
    const float* __restrict__ src_f, const float* __restrict__ tgt_f,
    const float4* __restrict__ cand, const float* __restrict__ aabb,
    float* __restrict__ out)
{
    const int inst = blockIdx.x & 1;
    const float* __restrict__ feats = inst ? tgt_f : src_f;
    float* __restrict__ outb = out + (size_t)inst * N_PTS * (2 * C_FEAT);
    const float4* __restrict__ cd = cand + inst * N_PTS;

    const int tid = threadIdx.x, wave = tid >> 6, lane = tid & 63;

    __shared__ float sab[NTILES * 6];                 // 3 KB
    __shared__ unsigned int slist[NWAVES][NTILES];    // packed (lb|tile), 2 KB
    __shared__ float qds[NWAVES][WQ][QCAP];           // 6 KB
    __shared__ int   qis[NWAVES][WQ][QCAP];           // 6 KB
    for (int i = tid; i < NTILES * 6; i += NTHREADS)
        sab[i] = aabb[inst * NTILES * 6 + i];
    __syncthreads();

    const int q0 = (blockIdx.x >> 1) * QPB + wave * WQ;  // sorted row
    float qx[WQ], qy[WQ], qz[WQ], qsq[WQ];
    int qor[WQ]; float W[WQ]; int cnt[WQ];
    #pragma unroll
    for (int q = 0; q < WQ; ++q) {
        const float4 c = cd[q0 + q];
        qx[q] = c.x; qy[q] = c.y; qz[q] = c.z;
        qor[q] = __float_as_int(c.w);
        qsq[q] = __fmaf_rn(c.z, c.z, __fmaf_rn(c.y, c.y, __fmul_rn(c.x, c.x)));
        W[q] = FLT_MAX;
        cnt[q] = 0;
    }

    const int ownt = q0 / TILE;   // tile containing the queries

    // ---- own tile: radix-select exact 11th distance -> W init + append --
    {
        const float4 c0 = cd[ownt * TILE + lane];
        const float4 c1 = cd[ownt * TILE + 64 + lane];

        unsigned k0[WQ], k1[WQ];
        #pragma unroll
        for (int q = 0; q < WQ; ++q) {
            float d0, d1;
            DIST_TO(c0, q, d0);
            DIST_TO(c1, q, d1);
            k0[q] = keyf(d0);
            k1[q] = keyf(d1);
        }
        #pragma unroll
        for (int q = 0; q < WQ; ++q) {
            unsigned pk_;
            RADIX11_2(k0[q], k1[q], pk_);
            W[q] = unkeyf(pk_);
        }
        // Appends: masks have ~11+ties bits total; fully parallel.
        APPEND_BATCH(c0);
        APPEND_BATCH(c1);
    }

    // ---- zigzag (near->far) survivor list: PER-QUERY point-to-box lb ----
    // keep tile iff exists q: lb_q - eps <= W[q] (W = exact own-tile 11th;
    // W only shrinks -> skip is safe). Entry packs minlb = min_q lb_q:
    // (bits & ~0xFF) | tile — minlb>=0 so uint order == lb order; unpacked
    // value rounds DOWN => recheck stays conservative.
    int nsurv = 0;
    #pragma unroll
    for (int g = 0; g < 4; ++g) {
        const int p = g * 64 + lane;
        const int o = (p >> 1) + 1;
        const int t = (p & 1) ? (ownt - o) : (ownt + o);
        bool ok = (t >= 0) && (t < NTILES);
        float mlb = 0.0f;
        if (ok) {
            const float tmnx = sab[t*6+0], tmny = sab[t*6+1], tmnz = sab[t*6+2];
            const float tmxx = sab[t*6+3], tmxy = sab[t*6+4], tmxz = sab[t*6+5];
            bool any = false;
            mlb = FLT_MAX;
            #pragma unroll
            for (int q = 0; q < WQ; ++q) {
                const float dx = fmaxf(0.f, fmaxf(tmnx - qx[q], qx[q] - tmxx));
                const float dy = fmaxf(0.f, fmaxf(tmny - qy[q], qy[q] - tmxy));
                const float dz = fmaxf(0.f, fmaxf(tmnz - qz[q], qz[q] - tmxz));
                float lb = dx * dx;
                lb = fmaf(dy, dy, lb);
                lb = fmaf(dz, dz, lb);
                any = any || ((lb - 1e-3f) <= W[q]);
                mlb = fminf(mlb, lb);
            }
            ok = any;
        }
        const unsigned long long mk = __ballot(ok);
        if (ok) {
            const int idx = nsurv + (int)__popcll(mk & ((1ull << lane) - 1ull));
            slist[wave][idx] = (__float_as_uint(mlb) & 0xFFFFFF00u) | (unsigned)t;
        }
        nsurv += (int)__popcll(mk);
    }

    // ---- scan survivors: 4-slot prefetch ring + LIVE recheck vs W ----
    float4 T0a, T0b, T1a, T1b, T2a, T2b, T3a, T3b;
    unsigned int u0 = 0, u1 = 0, u2 = 0, u3 = 0;
    {
        u0 = (0 < nsurv) ? slist[wave][0] : (unsigned)ownt;
        const int t0 = (int)(u0 & 0xFFu);
        T0a = cd[t0 * TILE + lane]; T0b = cd[t0 * TILE + 64 + lane];
        u1 = (1 < nsurv) ? slist[wave][1] : (unsigned)ownt;
        const int t1 = (int)(u1 & 0xFFu);
        T1a = cd[t1 * TILE + lane]; T1b = cd[t1 * TILE + 64 + lane];
        u2 = (2 < nsurv) ? slist[wave][2] : (unsigned)ownt;
        const int t2 = (int)(u2 & 0xFFu);
        T2a = cd[t2 * TILE + lane]; T2b = cd[t2 * TILE + 64 + lane];
        u3 = (3 < nsurv) ? slist[wave][3] : (unsigned)ownt;
        const int t3 = (int)(u3 & 0xFFu);
        T3a = cd[t3 * TILE + lane]; T3b = cd[t3 * TILE + 64 + lane];
    }
    #define SCAN_STEP(UA, TA, TB)                                           \
      {                                                                     \
        const unsigned uN = (s + 4 < nsurv) ? slist[wave][s + 4]            \
                                            : (unsigned)ownt;               \
        const int tn = (int)(uN & 0xFFu);                                   \
        if (__uint_as_float(UA & 0xFFFFFF00u) - 1e-3f <= WMAX4) {           \
            APPEND_BATCH(TA);                                               \
            APPEND_BATCH(TB);                                               \
        }                                                                   \
        UA = uN;                                                            \
        TA = cd[tn * TILE + lane]; TB = cd[tn * TILE + 64 + lane];          \
        ++s;                                                                \
      }
    int s = 0;
    while (s < nsurv) {
        SCAN_STEP(u0, T0a, T0b);
        if (s >= nsurv) break;
        SCAN_STEP(u1, T1a, T1b);
        if (s >= nsurv) break;
        SCAN_STEP(u2, T2a, T2b);
        if (s >= nsurv) break;
        SCAN_STEP(u3, T3a, T3b);
    }
    #undef SCAN_STEP

    // ---- final: per query, exact 11th + compact + bitonic sort + gather --
    // Sorted ascending lex (d, idx): rank 0 = self/near-twin (dropped
    // positionally, as before); ranks 1..10 -> feature columns 0..9.
    float M[WQ];
    #pragma unroll
    for (int q = 0; q < WQ; ++q) {
        COMPACT(q);                       // W[q] = exact final 11th; g>=11
        const int g_ = cnt[q];
        float dl = (lane < g_) ? qds[wave][q][lane] : FLT_MAX;
        int   il = (lane < g_) ? qis[wave][q][lane] : 0x7fffffff;
        #pragma unroll
        for (int k = 2; k <= 64; k <<= 1) {
            #pragma unroll
            for (int j = k >> 1; j > 0; j >>= 1) {
                const float pd = __shfl_xor(dl, j);
                const int   pi = __shfl_xor(il, j);
                const bool keepMin = (((lane & k) == 0) == ((lane & j) == 0));
                const bool mineGt = (dl > pd) || (dl == pd && il > pi);
                const bool take = keepMin ? mineGt : !mineGt;
                dl = take ? pd : dl;
                il = take ? pi : il;
            }
        }
        float fv = -FLT_MAX;
        if (lane >= 1 && lane <= KK - 1)
            fv = feats[(size_t)il * C_FEAT + (lane - 1)];
        #pragma unroll
        for (int off = 1; off < 64; off <<= 1)
            fv = fmaxf(fv, __shfl_xor(fv, off));
        M[q] = fv;
    }

    #pragma unroll
    for (int q = 0; q < WQ; ++q) {
        const int   row = qor[q];
        const float v   = feats[(size_t)row * C_FEAT + lane];
        outb[(size_t)row * (2 * C_FEAT) + lane]          = v;
        outb[(size_t)row * (2 * C_FEAT) + C_FEAT + lane] = M[q] - v;
    }
}

extern "C" void kernel_launch(void* const* d_in, const int* in_sizes, int n_in,
                              void* d_out, int out_size, void* d_ws, size_t ws_size,
                              hipStream_t stream) {
    const float* src_f = (const float*)d_in[0];
    const float* tgt_f = (const float*)d_in[1];
    const float* src_c = (const float*)d_in[2];
    const float* tgt_c = (const float*)d_in[3];
    float* out = (float*)d_out;

    char* ws = (char*)d_ws;
    float4* cand = (float4*)(ws + WS_CAND);
    float*  aabb = (float*) (ws + WS_AABB);
    int*    hist = (int*)   (ws + WS_HIST);

    hipMemsetAsync(hist, 0, 2 * NCELLS * sizeof(int), stream);
    hipLaunchKernelGGL(hist_kernel, dim3(128), dim3(256), 0, stream,
                       src_c, tgt_c, hist);
    hipLaunchKernelGGL(scan_kernel, dim3(2), dim3(1024), 0, stream, hist);
    hipLaunchKernelGGL(scatter_kernel, dim3(128), dim3(256), 0, stream,
                       src_c, tgt_c, hist, cand);
    hipLaunchKernelGGL(aabb_kernel, dim3(2 * NTILES), dim3(64), 0, stream,
                       cand, aabb);
    hipLaunchKernelGGL(knn_pool_kernel, dim3(2 * (N_PTS / QPB)), dim3(NTHREADS),
                       0, stream, src_f, tgt_f, cand, aabb, out);
}

// Round 16
// 172.454 us; speedup vs baseline: 1.2441x; 1.0228x over previous
//
#include <hip/hip_runtime.h>
#include <cfloat>
#include <math.h>

// Exact-replication KNN (k=10, +self) + rank-column gather max-pool.
// NUMERICS FROZEN (R3 pass, absmax 0.0): fp32 chains
//   sq  = fma(z,z, fma(y,y, rn(x*x)))
//   dot = fma(z,z', fma(y,y', rn(x*x')))
//   d   = fma(dot, -2, rn(sq_i+sq_j))    [== rn(sum - rn(2*dot)), 2*dot exact]
// Selection order = jax top_k = ascending lexicographic (d, orig_idx) —
// proven order-independent in R8/R9 (absmax 0.0, nondeterministic scatter).
//
// Round 26: DROP THE HEAVY PRE-GATE. R25 (queue-append scan) changed the
// cost model: a fat mask now costs a parallel prefix-append (~free), not
// popc(m) x 320cy serial inserts. The R24 pre-gate radix (32 serial ballot
// steps ~500cy) now over-fires in exactly the tail waves it was meant to
// help (loose W -> many heavy batches -> hundreds of radixes). Capacity
// compaction already computes the EXACT running 11th (tighter than any
// per-tile 11th) once per ~75 appends. So the scan path is now just:
// dist -> ballot vs W -> prefix append; W tightens only via compaction.
// Self-regulating: early fat masks fill the queue in ~2 tiles -> compact
// -> W = exact running 11th -> masks collapse. Post-compact burst fits:
// 11 + 64 = 75 < QCAP. Exactness unchanged (every discard had d > W >=
// running 11th >= final 11th; final bitonic identical) -> absmax 0.0.
// Kept: R14 init radix, R16 4-slot ring, R22 per-query lb, R25 queues.

#define N_PTS    16384
#define C_FEAT   64
#define KK       11
#define NCELLS   4096                 // 16^3 Morton cells
#define TILE     128                  // sorted points per tile
#define NTILES   (N_PTS / TILE)       // 128
#define WQ       4
#define NWAVES   4
#define NTHREADS (NWAVES * 64)
#define QPB      (NWAVES * WQ)        // 16 queries per block
#define QCAP     96                   // queue slots per query

// d_ws layout (bytes)
#define WS_CAND  0                            // float4[2][N_PTS]   512 KB
#define WS_AABB  (WS_CAND + 2*N_PTS*16)       // float[2][NTILES][6]  6 KB
#define WS_HIST  (WS_AABB + 2*NTILES*6*4)     // int[2][NCELLS]      32 KB

__device__ __forceinline__ int cell_of(float x, float y, float z) {
    int cx = (int)floorf((x + 4.5f) * (16.0f / 9.0f));
    int cy = (int)floorf((y + 4.5f) * (16.0f / 9.0f));
    int cz = (int)floorf((z + 4.5f) * (16.0f / 9.0f));
    cx = min(15, max(0, cx));
    cy = min(15, max(0, cy));
    cz = min(15, max(0, cz));
    int m = 0;
    #pragma unroll
    for (int b = 0; b < 4; ++b)
        m |= (((cx >> b) & 1) << (3 * b)) |
             (((cy >> b) & 1) << (3 * b + 1)) |
             (((cz >> b) & 1) << (3 * b + 2));
    return m;
}

// Monotone (order-preserving, bijective) float<->uint key.
__device__ __forceinline__ unsigned keyf(float f) {
    const unsigned u = __float_as_uint(f);
    return (u & 0x80000000u) ? ~u : (u | 0x80000000u);
}
__device__ __forceinline__ float unkeyf(unsigned k) {
    return __uint_as_float((k & 0x80000000u) ? (k ^ 0x80000000u) : ~k);
}

// 128 blocks x 256 thr, one point per thread. Global atomics into hist
// (pre-zeroed by hipMemsetAsync).
__global__ __launch_bounds__(256) void hist_kernel(
    const float* __restrict__ src_c, const float* __restrict__ tgt_c,
    int* __restrict__ hist)
{
    const int inst = blockIdx.x >> 6;           // 64 blocks per instance
    const float* __restrict__ coords = inst ? tgt_c : src_c;
    int* __restrict__ h = hist + inst * NCELLS;
    const int p = ((blockIdx.x & 63) << 8) + threadIdx.x;
    const float* c = coords + (size_t)p * 3;
    atomicAdd(&h[cell_of(c[0], c[1], c[2])], 1);
}

// One block per instance. Barrier scan; leaves h[cell] = exclusive base.
__global__ __launch_bounds__(1024) void scan_kernel(int* __restrict__ hist)
{
    const int inst = blockIdx.x;
    int* __restrict__ h = hist + inst * NCELLS;
    __shared__ int sd[1024];
    const int t = threadIdx.x;

    int v[4], ssum = 0;
    #pragma unroll
    for (int j = 0; j < 4; ++j) { v[j] = h[t * 4 + j]; ssum += v[j]; }
    sd[t] = ssum;
    __syncthreads();
    for (int off = 1; off < 1024; off <<= 1) {
        const int x = (t >= off) ? sd[t - off] : 0;
        __syncthreads();
        sd[t] += x;
        __syncthreads();
    }
    int base = sd[t] - ssum;
    #pragma unroll
    for (int j = 0; j < 4; ++j) { h[t * 4 + j] = base; base += v[j]; }
}

// 128 blocks x 256 thr. dst = atomicAdd(write-pointer). Within-cell order is
// nondeterministic — exactly as R8-R25 (selection proven order-independent).
__global__ __launch_bounds__(256) void scatter_kernel(
    const float* __restrict__ src_c, const float* __restrict__ tgt_c,
    int* __restrict__ hist, float4* __restrict__ cand)
{
    const int inst = blockIdx.x >> 6;
    const float* __restrict__ coords = inst ? tgt_c : src_c;
    int* __restrict__ h = hist + inst * NCELLS;
    float4* __restrict__ cb = cand + inst * N_PTS;
    const int p = ((blockIdx.x & 63) << 8) + threadIdx.x;
    const float* c = coords + (size_t)p * 3;
    const float x = c[0], y = c[1], z = c[2];
    const int dst = atomicAdd(&h[cell_of(x, y, z)], 1);
    cb[dst] = make_float4(x, y, z, __int_as_float(p));
}

__global__ void aabb_kernel(const float4* __restrict__ cand,
                            float* __restrict__ aabb) {
    const int it = blockIdx.x;                 // inst*NTILES + tile
    const int base = (it / NTILES) * N_PTS + (it % NTILES) * TILE;
    const int lane = threadIdx.x;              // 64 threads, 2 pts each
    float4 a = cand[base + lane], b = cand[base + 64 + lane];
    float mnx = fminf(a.x, b.x), mny = fminf(a.y, b.y), mnz = fminf(a.z, b.z);
    float mxx = fmaxf(a.x, b.x), mxy = fmaxf(a.y, b.y), mxz = fmaxf(a.z, b.z);
    #pragma unroll
    for (int off = 1; off < 64; off <<= 1) {
        mnx = fminf(mnx, __shfl_xor(mnx, off));
        mny = fminf(mny, __shfl_xor(mny, off));
        mnz = fminf(mnz, __shfl_xor(mnz, off));
        mxx = fmaxf(mxx, __shfl_xor(mxx, off));
        mxy = fmaxf(mxy, __shfl_xor(mxy, off));
        mxz = fmaxf(mxz, __shfl_xor(mxz, off));
    }
    if (lane == 0) {
        aabb[it * 6 + 0] = mnx; aabb[it * 6 + 1] = mny; aabb[it * 6 + 2] = mnz;
        aabb[it * 6 + 3] = mxx; aabb[it * 6 + 4] = mxy; aabb[it * 6 + 5] = mxz;
    }
}

// Frozen distance chain for candidate C vs query q (do not reorder).
#define DIST_TO(C, q, dout)                                                 \
  { const float csq_ = __fmaf_rn((C).z, (C).z, __fmaf_rn((C).y, (C).y,      \
                                 __fmul_rn((C).x, (C).x)));                 \
    float dot_ = __fmul_rn((C).x, qx[q]);                                   \
    dot_ = __fmaf_rn((C).y, qy[q], dot_);                                   \
    dot_ = __fmaf_rn((C).z, qz[q], dot_);                                   \
    (dout) = __fmaf_rn(dot_, -2.0f, __fadd_rn(qsq[q], csq_)); }

#define LMASK_LT ((1ull << lane) - 1ull)

// Exact 11th-smallest key of 128 wave-held keys (two regs).
#define RADIX11_2(K0, K1, PKOUT)                                            \
  { unsigned pkr_ = 0u;                                                     \
    for (int b_ = 31; b_ >= 0; --b_) {                                      \
      const unsigned mid_ = pkr_ | (1u << b_);                              \
      const int c_ = (int)__popcll(__ballot((K0) < mid_))                   \
                   + (int)__popcll(__ballot((K1) < mid_));                  \
      if (c_ < KK) pkr_ = mid_;                                             \
    }                                                                       \
    (PKOUT) = pkr_; }

// Compact query q's queue to entries <= its exact 11th; W[q] becomes the
// EXACT running 11th (queue holds all candidates <= every past W >= running
// 11th, so the 11 smallest seen are all present). Wave-local, no atomics.
// Same-wave ds read->write ordering is in-order (proven assumption R10+).
#define COMPACT(q)                                                          \
  { const int cc_ = cnt[q];                                                 \
    const int l1_ = 64 + lane;                                              \
    const float cd0_ = (lane < cc_) ? qds[wave][q][lane] : FLT_MAX;         \
    const int   ci0_ = (lane < cc_) ? qis[wave][q][lane] : 0x7fffffff;      \
    const float cd1_ = (l1_ < cc_) ? qds[wave][q][l1_] : FLT_MAX;           \
    const int   ci1_ = (l1_ < cc_) ? qis[wave][q][l1_] : 0x7fffffff;        \
    const unsigned ck0_ = keyf(cd0_), ck1_ = keyf(cd1_);                    \
    unsigned pk_;                                                           \
    RADIX11_2(ck0_, ck1_, pk_);                                             \
    W[q] = unkeyf(pk_);                                                     \
    const bool f0_ = (ck0_ <= pk_) && (lane < cc_);                         \
    const bool f1_ = (ck1_ <= pk_) && (l1_ < cc_);                          \
    const unsigned long long b0_ = __ballot(f0_), b1_ = __ballot(f1_);      \
    const int n0_ = (int)__popcll(b0_);                                     \
    if (f0_) { const int o_ = (int)__popcll(b0_ & LMASK_LT);                \
               qds[wave][q][o_] = cd0_; qis[wave][q][o_] = ci0_; }          \
    if (f1_) { const int o_ = n0_ + (int)__popcll(b1_ & LMASK_LT);          \
               qds[wave][q][o_] = cd1_; qis[wave][q][o_] = ci1_; }          \
    cnt[q] = n0_ + (int)__popcll(b1_); }

// One 64-candidate batch vs the wave's 4 queries: dist -> gate vs W ->
// capacity compact (rare) -> parallel prefix append. No per-candidate
// serial loop, no per-tile radix.
#define APPEND_BATCH(C)                                                     \
  {                                                                         \
    const float cx = (C).x, cy = (C).y, cz = (C).z;                         \
    const int corig = __float_as_int((C).w);                                \
    const float csq = __fmaf_rn(cz, cz, __fmaf_rn(cy, cy,                   \
                                __fmul_rn(cx, cx)));                        \
    _Pragma("unroll")                                                       \
    for (int q = 0; q < WQ; ++q) {                                          \
      float dot = __fmul_rn(cx, qx[q]);                                     \
      dot = __fmaf_rn(cy, qy[q], dot);                                      \
      dot = __fmaf_rn(cz, qz[q], dot);                                      \
      const float sum = __fadd_rn(qsq[q], csq);                             \
      const float d = __fmaf_rn(dot, -2.0f, sum);                           \
      unsigned long long m = __ballot(d <= W[q]);                           \
      if (m) {                                                              \
        if (cnt[q] + (int)__popcll(m) > QCAP) {                             \
          COMPACT(q);                                                       \
          m = __ballot(d <= W[q]);                                          \
        }                                                                   \
        const int base_ = cnt[q];                                           \
        const int o_ = base_ + (int)__popcll(m & LMASK_LT);                 \
        if (((m >> lane) & 1ull) && o_ < QCAP) {                            \
          qds[wave][q][o_] = d; qis[wave][q][o_] = corig;                   \
        }                                                                   \
        cnt[q] = min(base_ + (int)__popcll(m), QCAP);                       \
      }                                                                     \
    }                                                                       \
  }

#define WMAX4 fmaxf(fmaxf(W[0], W[1]), fmaxf(W[2], W[3]))

__global__ __launch_bounds__(NTHREADS) void knn_pool_kernel(
    const float* __restrict__ src_f, const float* __restrict__ tgt_f,
    const float4* __restrict__ cand, const float* __restrict__ aabb,
    float* __restrict__ out)
{
    const int inst = blockIdx.x & 1;
    const float* __restrict__ feats = inst ? tgt_f : src_f;
    float* __restrict__ outb = out + (size_t)inst * N_PTS * (2 * C_FEAT);
    const float4* __restrict__ cd = cand + inst * N_PTS;

    const int tid = threadIdx.x, wave = tid >> 6, lane = tid & 63;

    __shared__ float sab[NTILES * 6];                 // 3 KB
    __shared__ unsigned int slist[NWAVES][NTILES];    // packed (lb|tile), 2 KB
    __shared__ float qds[NWAVES][WQ][QCAP];           // 6 KB
    __shared__ int   qis[NWAVES][WQ][QCAP];           // 6 KB
    for (int i = tid; i < NTILES * 6; i += NTHREADS)
        sab[i] = aabb[inst * NTILES * 6 + i];
    __syncthreads();

    const int q0 = (blockIdx.x >> 1) * QPB + wave * WQ;  // sorted row
    float qx[WQ], qy[WQ], qz[WQ], qsq[WQ];
    int qor[WQ]; float W[WQ]; int cnt[WQ];
    #pragma unroll
    for (int q = 0; q < WQ; ++q) {
        const float4 c = cd[q0 + q];
        qx[q] = c.x; qy[q] = c.y; qz[q] = c.z;
        qor[q] = __float_as_int(c.w);
        qsq[q] = __fmaf_rn(c.z, c.z, __fmaf_rn(c.y, c.y, __fmul_rn(c.x, c.x)));
        W[q] = FLT_MAX;
        cnt[q] = 0;
    }

    const int ownt = q0 / TILE;   // tile containing the queries

    // ---- own tile: radix-select exact 11th distance -> W init + append --
    {
        const float4 c0 = cd[ownt * TILE + lane];
        const float4 c1 = cd[ownt * TILE + 64 + lane];

        unsigned k0[WQ], k1[WQ];
        #pragma unroll
        for (int q = 0; q < WQ; ++q) {
            float d0, d1;
            DIST_TO(c0, q, d0);
            DIST_TO(c1, q, d1);
            k0[q] = keyf(d0);
            k1[q] = keyf(d1);
        }
        #pragma unroll
        for (int q = 0; q < WQ; ++q) {
            unsigned pk_;
            RADIX11_2(k0[q], k1[q], pk_);
            W[q] = unkeyf(pk_);
        }
        // Appends: masks have ~11+ties bits total; fully parallel.
        APPEND_BATCH(c0);
        APPEND_BATCH(c1);
    }

    // ---- zigzag (near->far) survivor list: PER-QUERY point-to-box lb ----
    // keep tile iff exists q: lb_q - eps <= W[q] (W = exact own-tile 11th;
    // W only shrinks -> skip is safe). Entry packs minlb = min_q lb_q:
    // (bits & ~0xFF) | tile — minlb>=0 so uint order == lb order; unpacked
    // value rounds DOWN => recheck stays conservative.
    int nsurv = 0;
    #pragma unroll
    for (int g = 0; g < 4; ++g) {
        const int p = g * 64 + lane;
        const int o = (p >> 1) + 1;
        const int t = (p & 1) ? (ownt - o) : (ownt + o);
        bool ok = (t >= 0) && (t < NTILES);
        float mlb = 0.0f;
        if (ok) {
            const float tmnx = sab[t*6+0], tmny = sab[t*6+1], tmnz = sab[t*6+2];
            const float tmxx = sab[t*6+3], tmxy = sab[t*6+4], tmxz = sab[t*6+5];
            bool any = false;
            mlb = FLT_MAX;
            #pragma unroll
            for (int q = 0; q < WQ; ++q) {
                const float dx = fmaxf(0.f, fmaxf(tmnx - qx[q], qx[q] - tmxx));
                const float dy = fmaxf(0.f, fmaxf(tmny - qy[q], qy[q] - tmxy));
                const float dz = fmaxf(0.f, fmaxf(tmnz - qz[q], qz[q] - tmxz));
                float lb = dx * dx;
                lb = fmaf(dy, dy, lb);
                lb = fmaf(dz, dz, lb);
                any = any || ((lb - 1e-3f) <= W[q]);
                mlb = fminf(mlb, lb);
            }
            ok = any;
        }
        const unsigned long long mk = __ballot(ok);
        if (ok) {
            const int idx = nsurv + (int)__popcll(mk & ((1ull << lane) - 1ull));
            slist[wave][idx] = (__float_as_uint(mlb) & 0xFFFFFF00u) | (unsigned)t;
        }
        nsurv += (int)__popcll(mk);
    }

    // ---- scan survivors: 4-slot prefetch ring + LIVE recheck vs W ----
    float4 T0a, T0b, T1a, T1b, T2a, T2b, T3a, T3b;
    unsigned int u0 = 0, u1 = 0, u2 = 0, u3 = 0;
    {
        u0 = (0 < nsurv) ? slist[wave][0] : (unsigned)ownt;
        const int t0 = (int)(u0 & 0xFFu);
        T0a = cd[t0 * TILE + lane]; T0b = cd[t0 * TILE + 64 + lane];
        u1 = (1 < nsurv) ? slist[wave][1] : (unsigned)ownt;
        const int t1 = (int)(u1 & 0xFFu);
        T1a = cd[t1 * TILE + lane]; T1b = cd[t1 * TILE + 64 + lane];
        u2 = (2 < nsurv) ? slist[wave][2] : (unsigned)ownt;
        const int t2 = (int)(u2 & 0xFFu);
        T2a = cd[t2 * TILE + lane]; T2b = cd[t2 * TILE + 64 + lane];
        u3 = (3 < nsurv) ? slist[wave][3] : (unsigned)ownt;
        const int t3 = (int)(u3 & 0xFFu);
        T3a = cd[t3 * TILE + lane]; T3b = cd[t3 * TILE + 64 + lane];
    }
    #define SCAN_STEP(UA, TA, TB)                                           \
      {                                                                     \
        const unsigned uN = (s + 4 < nsurv) ? slist[wave][s + 4]            \
                                            : (unsigned)ownt;               \
        const int tn = (int)(uN & 0xFFu);                                   \
        if (__uint_as_float(UA & 0xFFFFFF00u) - 1e-3f <= WMAX4) {           \
            APPEND_BATCH(TA);                                               \
            APPEND_BATCH(TB);                                               \
        }                                                                   \
        UA = uN;                                                            \
        TA = cd[tn * TILE + lane]; TB = cd[tn * TILE + 64 + lane];          \
        ++s;                                                                \
      }
    int s = 0;
    while (s < nsurv) {
        SCAN_STEP(u0, T0a, T0b);
        if (s >= nsurv) break;
        SCAN_STEP(u1, T1a, T1b);
        if (s >= nsurv) break;
        SCAN_STEP(u2, T2a, T2b);
        if (s >= nsurv) break;
        SCAN_STEP(u3, T3a, T3b);
    }
    #undef SCAN_STEP

    // ---- final: per query, exact 11th + compact + bitonic sort + gather --
    // Sorted ascending lex (d, idx): rank 0 = self/near-twin (dropped
    // positionally, as before); ranks 1..10 -> feature columns 0..9.
    float M[WQ];
    #pragma unroll
    for (int q = 0; q < WQ; ++q) {
        COMPACT(q);                       // W[q] = exact final 11th; g>=11
        const int g_ = cnt[q];
        float dl = (lane < g_) ? qds[wave][q][lane] : FLT_MAX;
        int   il = (lane < g_) ? qis[wave][q][lane] : 0x7fffffff;
        #pragma unroll
        for (int k = 2; k <= 64; k <<= 1) {
            #pragma unroll
            for (int j = k >> 1; j > 0; j >>= 1) {
                const float pd = __shfl_xor(dl, j);
                const int   pi = __shfl_xor(il, j);
                const bool keepMin = (((lane & k) == 0) == ((lane & j) == 0));
                const bool mineGt = (dl > pd) || (dl == pd && il > pi);
                const bool take = keepMin ? mineGt : !mineGt;
                dl = take ? pd : dl;
                il = take ? pi : il;
            }
        }
        float fv = -FLT_MAX;
        if (lane >= 1 && lane <= KK - 1)
            fv = feats[(size_t)il * C_FEAT + (lane - 1)];
        #pragma unroll
        for (int off = 1; off < 64; off <<= 1)
            fv = fmaxf(fv, __shfl_xor(fv, off));
        M[q] = fv;
    }

    #pragma unroll
    for (int q = 0; q < WQ; ++q) {
        const int   row = qor[q];
        const float v   = feats[(size_t)row * C_FEAT + lane];
        outb[(size_t)row * (2 * C_FEAT) + lane]          = v;
        outb[(size_t)row * (2 * C_FEAT) + C_FEAT + lane] = M[q] - v;
    }
}

extern "C" void kernel_launch(void* const* d_in, const int* in_sizes, int n_in,
                              void* d_out, int out_size, void* d_ws, size_t ws_size,
                              hipStream_t stream) {
    const float* src_f = (const float*)d_in[0];
    const float* tgt_f = (const float*)d_in[1];
    const float* src_c = (const float*)d_in[2];
    const float* tgt_c = (const float*)d_in[3];
    float* out = (float*)d_out;

    char* ws = (char*)d_ws;
    float4* cand = (float4*)(ws + WS_CAND);
    float*  aabb = (float*) (ws + WS_AABB);
    int*    hist = (int*)   (ws + WS_HIST);

    hipMemsetAsync(hist, 0, 2 * NCELLS * sizeof(int), stream);
    hipLaunchKernelGGL(hist_kernel, dim3(128), dim3(256), 0, stream,
                       src_c, tgt_c, hist);
    hipLaunchKernelGGL(scan_kernel, dim3(2), dim3(1024), 0, stream, hist);
    hipLaunchKernelGGL(scatter_kernel, dim3(128), dim3(256), 0, stream,
                       src_c, tgt_c, hist, cand);
    hipLaunchKernelGGL(aabb_kernel, dim3(2 * NTILES), dim3(64), 0, stream,
                       cand, aabb);
    hipLaunchKernelGGL(knn_pool_kernel, dim3(2 * (N_PTS / QPB)), dim3(NTHREADS),
                       0, stream, src_f, tgt_f, cand, aabb, out);
}

// Round 17
// 156.547 us; speedup vs baseline: 1.3705x; 1.1016x over previous
//
#include <hip/hip_runtime.h>
#include <cfloat>
#include <math.h>

// Exact-replication KNN (k=10, +self) + rank-column gather max-pool.
// NUMERICS FROZEN (R3 pass, absmax 0.0): fp32 chains
//   sq  = fma(z,z, fma(y,y, rn(x*x)))
//   dot = fma(z,z', fma(y,y', rn(x*x')))
//   d   = fma(dot, -2, rn(sq_i+sq_j))    [== rn(sum - rn(2*dot)), 2*dot exact]
// Selection order = jax top_k = ascending lexicographic (d, orig_idx) —
// proven order-independent in R8/R9 (absmax 0.0, nondeterministic scatter).
//
// Round 27: WQ 4 -> 2 (QPB 16 -> 8, grid 2048 -> 4096 = 2x residency ->
// blocks stream). The tail wave's cost = survivor-set size x per-tile work
// for WQ queries; both halve at WQ=2 (the exists-q union gate over 2
// clustered queries admits far fewer tiles — the R22 union pathology
// attacked structurally). R25/R26 removed the old blocker: the queue+radix
// pipeline has no lane->query binding and no per-wave k=11 floor (which
// sank R15/R20), so WQ is now a near-parameter. Total (tile,query)
// distance work unchanged; only shared-tile LOADS duplicate (cand = 512KB
// / instance, L2-resident; QPB=8 keeps block-level clustering, unlike
// R20's QPB=4 FETCH explosion). Selection machinery untouched -> exact.
// Kept: R14 init radix, R16 4-slot ring, R22 per-query lb, R25 queues,
// R26 no-pre-gate.

#define N_PTS    16384
#define C_FEAT   64
#define KK       11
#define NCELLS   4096                 // 16^3 Morton cells
#define TILE     128                  // sorted points per tile
#define NTILES   (N_PTS / TILE)       // 128
#define WQ       2
#define NWAVES   4
#define NTHREADS (NWAVES * 64)
#define QPB      (NWAVES * WQ)        // 8 queries per block
#define QCAP     96                   // queue slots per query

// d_ws layout (bytes)
#define WS_CAND  0                            // float4[2][N_PTS]   512 KB
#define WS_AABB  (WS_CAND + 2*N_PTS*16)       // float[2][NTILES][6]  6 KB
#define WS_HIST  (WS_AABB + 2*NTILES*6*4)     // int[2][NCELLS]      32 KB

__device__ __forceinline__ int cell_of(float x, float y, float z) {
    int cx = (int)floorf((x + 4.5f) * (16.0f / 9.0f));
    int cy = (int)floorf((y + 4.5f) * (16.0f / 9.0f));
    int cz = (int)floorf((z + 4.5f) * (16.0f / 9.0f));
    cx = min(15, max(0, cx));
    cy = min(15, max(0, cy));
    cz = min(15, max(0, cz));
    int m = 0;
    #pragma unroll
    for (int b = 0; b < 4; ++b)
        m |= (((cx >> b) & 1) << (3 * b)) |
             (((cy >> b) & 1) << (3 * b + 1)) |
             (((cz >> b) & 1) << (3 * b + 2));
    return m;
}

// Monotone (order-preserving, bijective) float<->uint key.
__device__ __forceinline__ unsigned keyf(float f) {
    const unsigned u = __float_as_uint(f);
    return (u & 0x80000000u) ? ~u : (u | 0x80000000u);
}
__device__ __forceinline__ float unkeyf(unsigned k) {
    return __uint_as_float((k & 0x80000000u) ? (k ^ 0x80000000u) : ~k);
}

// 128 blocks x 256 thr, one point per thread. Global atomics into hist
// (pre-zeroed by hipMemsetAsync).
__global__ __launch_bounds__(256) void hist_kernel(
    const float* __restrict__ src_c, const float* __restrict__ tgt_c,
    int* __restrict__ hist)
{
    const int inst = blockIdx.x >> 6;           // 64 blocks per instance
    const float* __restrict__ coords = inst ? tgt_c : src_c;
    int* __restrict__ h = hist + inst * NCELLS;
    const int p = ((blockIdx.x & 63) << 8) + threadIdx.x;
    const float* c = coords + (size_t)p * 3;
    atomicAdd(&h[cell_of(c[0], c[1], c[2])], 1);
}

// One block per instance. Barrier scan; leaves h[cell] = exclusive base.
__global__ __launch_bounds__(1024) void scan_kernel(int* __restrict__ hist)
{
    const int inst = blockIdx.x;
    int* __restrict__ h = hist + inst * NCELLS;
    __shared__ int sd[1024];
    const int t = threadIdx.x;

    int v[4], ssum = 0;
    #pragma unroll
    for (int j = 0; j < 4; ++j) { v[j] = h[t * 4 + j]; ssum += v[j]; }
    sd[t] = ssum;
    __syncthreads();
    for (int off = 1; off < 1024; off <<= 1) {
        const int x = (t >= off) ? sd[t - off] : 0;
        __syncthreads();
        sd[t] += x;
        __syncthreads();
    }
    int base = sd[t] - ssum;
    #pragma unroll
    for (int j = 0; j < 4; ++j) { h[t * 4 + j] = base; base += v[j]; }
}

// 128 blocks x 256 thr. dst = atomicAdd(write-pointer). Within-cell order is
// nondeterministic — exactly as R8-R26 (selection proven order-independent).
__global__ __launch_bounds__(256) void scatter_kernel(
    const float* __restrict__ src_c, const float* __restrict__ tgt_c,
    int* __restrict__ hist, float4* __restrict__ cand)
{
    const int inst = blockIdx.x >> 6;
    const float* __restrict__ coords = inst ? tgt_c : src_c;
    int* __restrict__ h = hist + inst * NCELLS;
    float4* __restrict__ cb = cand + inst * N_PTS;
    const int p = ((blockIdx.x & 63) << 8) + threadIdx.x;
    const float* c = coords + (size_t)p * 3;
    const float x = c[0], y = c[1], z = c[2];
    const int dst = atomicAdd(&h[cell_of(x, y, z)], 1);
    cb[dst] = make_float4(x, y, z, __int_as_float(p));
}

__global__ void aabb_kernel(const float4* __restrict__ cand,
                            float* __restrict__ aabb) {
    const int it = blockIdx.x;                 // inst*NTILES + tile
    const int base = (it / NTILES) * N_PTS + (it % NTILES) * TILE;
    const int lane = threadIdx.x;              // 64 threads, 2 pts each
    float4 a = cand[base + lane], b = cand[base + 64 + lane];
    float mnx = fminf(a.x, b.x), mny = fminf(a.y, b.y), mnz = fminf(a.z, b.z);
    float mxx = fmaxf(a.x, b.x), mxy = fmaxf(a.y, b.y), mxz = fmaxf(a.z, b.z);
    #pragma unroll
    for (int off = 1; off < 64; off <<= 1) {
        mnx = fminf(mnx, __shfl_xor(mnx, off));
        mny = fminf(mny, __shfl_xor(mny, off));
        mnz = fminf(mnz, __shfl_xor(mnz, off));
        mxx = fmaxf(mxx, __shfl_xor(mxx, off));
        mxy = fmaxf(mxy, __shfl_xor(mxy, off));
        mxz = fmaxf(mxz, __shfl_xor(mxz, off));
    }
    if (lane == 0) {
        aabb[it * 6 + 0] = mnx; aabb[it * 6 + 1] = mny; aabb[it * 6 + 2] = mnz;
        aabb[it * 6 + 3] = mxx; aabb[it * 6 + 4] = mxy; aabb[it * 6 + 5] = mxz;
    }
}

// Frozen distance chain for candidate C vs query q (do not reorder).
#define DIST_TO(C, q, dout)                                                 \
  { const float csq_ = __fmaf_rn((C).z, (C).z, __fmaf_rn((C).y, (C).y,      \
                                 __fmul_rn((C).x, (C).x)));                 \
    float dot_ = __fmul_rn((C).x, qx[q]);                                   \
    dot_ = __fmaf_rn((C).y, qy[q], dot_);                                   \
    dot_ = __fmaf_rn((C).z, qz[q], dot_);                                   \
    (dout) = __fmaf_rn(dot_, -2.0f, __fadd_rn(qsq[q], csq_)); }

#define LMASK_LT ((1ull << lane) - 1ull)

// Exact 11th-smallest key of 128 wave-held keys (two regs).
#define RADIX11_2(K0, K1, PKOUT)                                            \
  { unsigned pkr_ = 0u;                                                     \
    for (int b_ = 31; b_ >= 0; --b_) {                                      \
      const unsigned mid_ = pkr_ | (1u << b_);                              \
      const int c_ = (int)__popcll(__ballot((K0) < mid_))                   \
                   + (int)__popcll(__ballot((K1) < mid_));                  \
      if (c_ < KK) pkr_ = mid_;                                             \
    }                                                                       \
    (PKOUT) = pkr_; }

// Compact query q's queue to entries <= its exact 11th; W[q] becomes the
// EXACT running 11th (queue holds all candidates <= every past W >= running
// 11th, so the 11 smallest seen are all present). Wave-local, no atomics.
// Same-wave ds read->write ordering is in-order (proven assumption R10+).
#define COMPACT(q)                                                          \
  { const int cc_ = cnt[q];                                                 \
    const int l1_ = 64 + lane;                                              \
    const float cd0_ = (lane < cc_) ? qds[wave][q][lane] : FLT_MAX;         \
    const int   ci0_ = (lane < cc_) ? qis[wave][q][lane] : 0x7fffffff;      \
    const float cd1_ = (l1_ < cc_) ? qds[wave][q][l1_] : FLT_MAX;           \
    const int   ci1_ = (l1_ < cc_) ? qis[wave][q][l1_] : 0x7fffffff;        \
    const unsigned ck0_ = keyf(cd0_), ck1_ = keyf(cd1_);                    \
    unsigned pk_;                                                           \
    RADIX11_2(ck0_, ck1_, pk_);                                             \
    W[q] = unkeyf(pk_);                                                     \
    const bool f0_ = (ck0_ <= pk_) && (lane < cc_);                         \
    const bool f1_ = (ck1_ <= pk_) && (l1_ < cc_);                          \
    const unsigned long long b0_ = __ballot(f0_), b1_ = __ballot(f1_);      \
    const int n0_ = (int)__popcll(b0_);                                     \
    if (f0_) { const int o_ = (int)__popcll(b0_ & LMASK_LT);                \
               qds[wave][q][o_] = cd0_; qis[wave][q][o_] = ci0_; }          \
    if (f1_) { const int o_ = n0_ + (int)__popcll(b1_ & LMASK_LT);          \
               qds[wave][q][o_] = cd1_; qis[wave][q][o_] = ci1_; }          \
    cnt[q] = n0_ + (int)__popcll(b1_); }

// One 64-candidate batch vs the wave's WQ queries: dist -> gate vs W ->
// capacity compact (rare) -> parallel prefix append. No per-candidate
// serial loop, no per-tile radix.
#define APPEND_BATCH(C)                                                     \
  {                                                                         \
    const float cx = (C).x, cy = (C).y, cz = (C).z;                         \
    const int corig = __float_as_int((C).w);                                \
    const float csq = __fmaf_rn(cz, cz, __fmaf_rn(cy, cy,                   \
                                __fmul_rn(cx, cx)));                        \
    _Pragma("unroll")                                                       \
    for (int q = 0; q < WQ; ++q) {                                          \
      float dot = __fmul_rn(cx, qx[q]);                                     \
      dot = __fmaf_rn(cy, qy[q], dot);                                      \
      dot = __fmaf_rn(cz, qz[q], dot);                                      \
      const float sum = __fadd_rn(qsq[q], csq);                             \
      const float d = __fmaf_rn(dot, -2.0f, sum);                           \
      unsigned long long m = __ballot(d <= W[q]);                           \
      if (m) {                                                              \
        if (cnt[q] + (int)__popcll(m) > QCAP) {                             \
          COMPACT(q);                                                       \
          m = __ballot(d <= W[q]);                                          \
        }                                                                   \
        const int base_ = cnt[q];                                           \
        const int o_ = base_ + (int)__popcll(m & LMASK_LT);                 \
        if (((m >> lane) & 1ull) && o_ < QCAP) {                            \
          qds[wave][q][o_] = d; qis[wave][q][o_] = corig;                   \
        }                                                                   \
        cnt[q] = min(base_ + (int)__popcll(m), QCAP);                      \
      }                                                                     \
    }                                                                       \
  }

#define WMAXQ fmaxf(W[0], W[1])

__global__ __launch_bounds__(NTHREADS) void knn_pool_kernel(
    const float* __restrict__ src_f, const float* __restrict__ tgt_f,
    const float4* __restrict__ cand, const float* __restrict__ aabb,
    float* __restrict__ out)
{
    const int inst = blockIdx.x & 1;
    const float* __restrict__ feats = inst ? tgt_f : src_f;
    float* __restrict__ outb = out + (size_t)inst * N_PTS * (2 * C_FEAT);
    const float4* __restrict__ cd = cand + inst * N_PTS;

    const int tid = threadIdx.x, wave = tid >> 6, lane = tid & 63;

    __shared__ float sab[NTILES * 6];                 // 3 KB
    __shared__ unsigned int slist[NWAVES][NTILES];    // packed (lb|tile), 2 KB
    __shared__ float qds[NWAVES][WQ][QCAP];           // 3 KB
    __shared__ int   qis[NWAVES][WQ][QCAP];           // 3 KB
    for (int i = tid; i < NTILES * 6; i += NTHREADS)
        sab[i] = aabb[inst * NTILES * 6 + i];
    __syncthreads();

    const int q0 = (blockIdx.x >> 1) * QPB + wave * WQ;  // sorted row
    float qx[WQ], qy[WQ], qz[WQ], qsq[WQ];
    int qor[WQ]; float W[WQ]; int cnt[WQ];
    #pragma unroll
    for (int q = 0; q < WQ; ++q) {
        const float4 c = cd[q0 + q];
        qx[q] = c.x; qy[q] = c.y; qz[q] = c.z;
        qor[q] = __float_as_int(c.w);
        qsq[q] = __fmaf_rn(c.z, c.z, __fmaf_rn(c.y, c.y, __fmul_rn(c.x, c.x)));
        W[q] = FLT_MAX;
        cnt[q] = 0;
    }

    const int ownt = q0 / TILE;   // tile containing the queries

    // ---- own tile: radix-select exact 11th distance -> W init + append --
    {
        const float4 c0 = cd[ownt * TILE + lane];
        const float4 c1 = cd[ownt * TILE + 64 + lane];

        unsigned k0[WQ], k1[WQ];
        #pragma unroll
        for (int q = 0; q < WQ; ++q) {
            float d0, d1;
            DIST_TO(c0, q, d0);
            DIST_TO(c1, q, d1);
            k0[q] = keyf(d0);
            k1[q] = keyf(d1);
        }
        #pragma unroll
        for (int q = 0; q < WQ; ++q) {
            unsigned pk_;
            RADIX11_2(k0[q], k1[q], pk_);
            W[q] = unkeyf(pk_);
        }
        // Appends: masks have ~11+ties bits total; fully parallel.
        APPEND_BATCH(c0);
        APPEND_BATCH(c1);
    }

    // ---- zigzag (near->far) survivor list: PER-QUERY point-to-box lb ----
    // keep tile iff exists q: lb_q - eps <= W[q] (W = exact own-tile 11th;
    // W only shrinks -> skip is safe). Entry packs minlb = min_q lb_q:
    // (bits & ~0xFF) | tile — minlb>=0 so uint order == lb order; unpacked
    // value rounds DOWN => recheck stays conservative.
    int nsurv = 0;
    #pragma unroll
    for (int g = 0; g < 4; ++g) {
        const int p = g * 64 + lane;
        const int o = (p >> 1) + 1;
        const int t = (p & 1) ? (ownt - o) : (ownt + o);
        bool ok = (t >= 0) && (t < NTILES);
        float mlb = 0.0f;
        if (ok) {
            const float tmnx = sab[t*6+0], tmny = sab[t*6+1], tmnz = sab[t*6+2];
            const float tmxx = sab[t*6+3], tmxy = sab[t*6+4], tmxz = sab[t*6+5];
            bool any = false;
            mlb = FLT_MAX;
            #pragma unroll
            for (int q = 0; q < WQ; ++q) {
                const float dx = fmaxf(0.f, fmaxf(tmnx - qx[q], qx[q] - tmxx));
                const float dy = fmaxf(0.f, fmaxf(tmny - qy[q], qy[q] - tmxy));
                const float dz = fmaxf(0.f, fmaxf(tmnz - qz[q], qz[q] - tmxz));
                float lb = dx * dx;
                lb = fmaf(dy, dy, lb);
                lb = fmaf(dz, dz, lb);
                any = any || ((lb - 1e-3f) <= W[q]);
                mlb = fminf(mlb, lb);
            }
            ok = any;
        }
        const unsigned long long mk = __ballot(ok);
        if (ok) {
            const int idx = nsurv + (int)__popcll(mk & ((1ull << lane) - 1ull));
            slist[wave][idx] = (__float_as_uint(mlb) & 0xFFFFFF00u) | (unsigned)t;
        }
        nsurv += (int)__popcll(mk);
    }

    // ---- scan survivors: 4-slot prefetch ring + LIVE recheck vs W ----
    float4 T0a, T0b, T1a, T1b, T2a, T2b, T3a, T3b;
    unsigned int u0 = 0, u1 = 0, u2 = 0, u3 = 0;
    {
        u0 = (0 < nsurv) ? slist[wave][0] : (unsigned)ownt;
        const int t0 = (int)(u0 & 0xFFu);
        T0a = cd[t0 * TILE + lane]; T0b = cd[t0 * TILE + 64 + lane];
        u1 = (1 < nsurv) ? slist[wave][1] : (unsigned)ownt;
        const int t1 = (int)(u1 & 0xFFu);
        T1a = cd[t1 * TILE + lane]; T1b = cd[t1 * TILE + 64 + lane];
        u2 = (2 < nsurv) ? slist[wave][2] : (unsigned)ownt;
        const int t2 = (int)(u2 & 0xFFu);
        T2a = cd[t2 * TILE + lane]; T2b = cd[t2 * TILE + 64 + lane];
        u3 = (3 < nsurv) ? slist[wave][3] : (unsigned)ownt;
        const int t3 = (int)(u3 & 0xFFu);
        T3a = cd[t3 * TILE + lane]; T3b = cd[t3 * TILE + 64 + lane];
    }
    #define SCAN_STEP(UA, TA, TB)                                           \
      {                                                                     \
        const unsigned uN = (s + 4 < nsurv) ? slist[wave][s + 4]            \
                                            : (unsigned)ownt;               \
        const int tn = (int)(uN & 0xFFu);                                   \
        if (__uint_as_float(UA & 0xFFFFFF00u) - 1e-3f <= WMAXQ) {           \
            APPEND_BATCH(TA);                                               \
            APPEND_BATCH(TB);                                               \
        }                                                                   \
        UA = uN;                                                            \
        TA = cd[tn * TILE + lane]; TB = cd[tn * TILE + 64 + lane];          \
        ++s;                                                                \
      }
    int s = 0;
    while (s < nsurv) {
        SCAN_STEP(u0, T0a, T0b);
        if (s >= nsurv) break;
        SCAN_STEP(u1, T1a, T1b);
        if (s >= nsurv) break;
        SCAN_STEP(u2, T2a, T2b);
        if (s >= nsurv) break;
        SCAN_STEP(u3, T3a, T3b);
    }
    #undef SCAN_STEP

    // ---- final: per query, exact 11th + compact + bitonic sort + gather --
    // Sorted ascending lex (d, idx): rank 0 = self/near-twin (dropped
    // positionally, as before); ranks 1..10 -> feature columns 0..9.
    float M[WQ];
    #pragma unroll
    for (int q = 0; q < WQ; ++q) {
        COMPACT(q);                       // W[q] = exact final 11th; g>=11
        const int g_ = cnt[q];
        float dl = (lane < g_) ? qds[wave][q][lane] : FLT_MAX;
        int   il = (lane < g_) ? qis[wave][q][lane] : 0x7fffffff;
        #pragma unroll
        for (int k = 2; k <= 64; k <<= 1) {
            #pragma unroll
            for (int j = k >> 1; j > 0; j >>= 1) {
                const float pd = __shfl_xor(dl, j);
                const int   pi = __shfl_xor(il, j);
                const bool keepMin = (((lane & k) == 0) == ((lane & j) == 0));
                const bool mineGt = (dl > pd) || (dl == pd && il > pi);
                const bool take = keepMin ? mineGt : !mineGt;
                dl = take ? pd : dl;
                il = take ? pi : il;
            }
        }
        float fv = -FLT_MAX;
        if (lane >= 1 && lane <= KK - 1)
            fv = feats[(size_t)il * C_FEAT + (lane - 1)];
        #pragma unroll
        for (int off = 1; off < 64; off <<= 1)
            fv = fmaxf(fv, __shfl_xor(fv, off));
        M[q] = fv;
    }

    #pragma unroll
    for (int q = 0; q < WQ; ++q) {
        const int   row = qor[q];
        const float v   = feats[(size_t)row * C_FEAT + lane];
        outb[(size_t)row * (2 * C_FEAT) + lane]          = v;
        outb[(size_t)row * (2 * C_FEAT) + C_FEAT + lane] = M[q] - v;
    }
}

extern "C" void kernel_launch(void* const* d_in, const int* in_sizes, int n_in,
                              void* d_out, int out_size, void* d_ws, size_t ws_size,
                              hipStream_t stream) {
    const float* src_f = (const float*)d_in[0];
    const float* tgt_f = (const float*)d_in[1];
    const float* src_c = (const float*)d_in[2];
    const float* tgt_c = (const float*)d_in[3];
    float* out = (float*)d_out;

    char* ws = (char*)d_ws;
    float4* cand = (float4*)(ws + WS_CAND);
    float*  aabb = (float*) (ws + WS_AABB);
    int*    hist = (int*)   (ws + WS_HIST);

    hipMemsetAsync(hist, 0, 2 * NCELLS * sizeof(int), stream);
    hipLaunchKernelGGL(hist_kernel, dim3(128), dim3(256), 0, stream,
                       src_c, tgt_c, hist);
    hipLaunchKernelGGL(scan_kernel, dim3(2), dim3(1024), 0, stream, hist);
    hipLaunchKernelGGL(scatter_kernel, dim3(128), dim3(256), 0, stream,
                       src_c, tgt_c, hist, cand);
    hipLaunchKernelGGL(aabb_kernel, dim3(2 * NTILES), dim3(64), 0, stream,
                       cand, aabb);
    hipLaunchKernelGGL(knn_pool_kernel, dim3(2 * (N_PTS / QPB)), dim3(NTHREADS),
                       0, stream, src_f, tgt_f, cand, aabb, out);
}

// Round 18
// 149.711 us; speedup vs baseline: 1.4331x; 1.0457x over previous
//
#include <hip/hip_runtime.h>
#include <cfloat>
#include <math.h>

// Exact-replication KNN (k=10, +self) + rank-column gather max-pool.
// NUMERICS FROZEN (R3 pass, absmax 0.0): fp32 chains
//   sq  = fma(z,z, fma(y,y, rn(x*x)))
//   dot = fma(z,z', fma(y,y', rn(x*x')))
//   d   = fma(dot, -2, rn(sq_i+sq_j))    [== rn(sum - rn(2*dot)), 2*dot exact]
// Selection order = jax top_k = ascending lexicographic (d, orig_idx) —
// proven order-independent in R8/R9 (absmax 0.0, nondeterministic scatter).
//
// Round 28: WQ 2 -> 1 (QPB 4, grid 8192 = 4x residency). R27 confirmed the
// lever: tail cost = survivor-set x per-tile work, both shrink with WQ.
// At WQ=1 the tile gate is single-query (tightest), per-tile scan work
// halves again, and the tail wave pays only for the worst single query.
// Counter-force: per-wave fixed costs (survivor build, final sort)
// duplicate across 2x waves; tile loads duplicate (cand 512KB L2-resident,
// HBM at 4% of peak -> absorbed). No cross-wave machinery, no overflow
// path (unlike R20). Selection machinery untouched -> exact, absmax 0.0.
// Kept: R14 init radix, R16 4-slot ring, R22 per-query lb, R25 queues,
// R26 no-pre-gate, R27 block clustering.

#define N_PTS    16384
#define C_FEAT   64
#define KK       11
#define NCELLS   4096                 // 16^3 Morton cells
#define TILE     128                  // sorted points per tile
#define NTILES   (N_PTS / TILE)       // 128
#define WQ       1
#define NWAVES   4
#define NTHREADS (NWAVES * 64)
#define QPB      (NWAVES * WQ)        // 4 queries per block
#define QCAP     96                   // queue slots per query

// d_ws layout (bytes)
#define WS_CAND  0                            // float4[2][N_PTS]   512 KB
#define WS_AABB  (WS_CAND + 2*N_PTS*16)       // float[2][NTILES][6]  6 KB
#define WS_HIST  (WS_AABB + 2*NTILES*6*4)     // int[2][NCELLS]      32 KB

__device__ __forceinline__ int cell_of(float x, float y, float z) {
    int cx = (int)floorf((x + 4.5f) * (16.0f / 9.0f));
    int cy = (int)floorf((y + 4.5f) * (16.0f / 9.0f));
    int cz = (int)floorf((z + 4.5f) * (16.0f / 9.0f));
    cx = min(15, max(0, cx));
    cy = min(15, max(0, cy));
    cz = min(15, max(0, cz));
    int m = 0;
    #pragma unroll
    for (int b = 0; b < 4; ++b)
        m |= (((cx >> b) & 1) << (3 * b)) |
             (((cy >> b) & 1) << (3 * b + 1)) |
             (((cz >> b) & 1) << (3 * b + 2));
    return m;
}

// Monotone (order-preserving, bijective) float<->uint key.
__device__ __forceinline__ unsigned keyf(float f) {
    const unsigned u = __float_as_uint(f);
    return (u & 0x80000000u) ? ~u : (u | 0x80000000u);
}
__device__ __forceinline__ float unkeyf(unsigned k) {
    return __uint_as_float((k & 0x80000000u) ? (k ^ 0x80000000u) : ~k);
}

// 128 blocks x 256 thr, one point per thread. Global atomics into hist
// (pre-zeroed by hipMemsetAsync).
__global__ __launch_bounds__(256) void hist_kernel(
    const float* __restrict__ src_c, const float* __restrict__ tgt_c,
    int* __restrict__ hist)
{
    const int inst = blockIdx.x >> 6;           // 64 blocks per instance
    const float* __restrict__ coords = inst ? tgt_c : src_c;
    int* __restrict__ h = hist + inst * NCELLS;
    const int p = ((blockIdx.x & 63) << 8) + threadIdx.x;
    const float* c = coords + (size_t)p * 3;
    atomicAdd(&h[cell_of(c[0], c[1], c[2])], 1);
}

// One block per instance. Barrier scan; leaves h[cell] = exclusive base.
__global__ __launch_bounds__(1024) void scan_kernel(int* __restrict__ hist)
{
    const int inst = blockIdx.x;
    int* __restrict__ h = hist + inst * NCELLS;
    __shared__ int sd[1024];
    const int t = threadIdx.x;

    int v[4], ssum = 0;
    #pragma unroll
    for (int j = 0; j < 4; ++j) { v[j] = h[t * 4 + j]; ssum += v[j]; }
    sd[t] = ssum;
    __syncthreads();
    for (int off = 1; off < 1024; off <<= 1) {
        const int x = (t >= off) ? sd[t - off] : 0;
        __syncthreads();
        sd[t] += x;
        __syncthreads();
    }
    int base = sd[t] - ssum;
    #pragma unroll
    for (int j = 0; j < 4; ++j) { h[t * 4 + j] = base; base += v[j]; }
}

// 128 blocks x 256 thr. dst = atomicAdd(write-pointer). Within-cell order is
// nondeterministic — exactly as R8-R27 (selection proven order-independent).
__global__ __launch_bounds__(256) void scatter_kernel(
    const float* __restrict__ src_c, const float* __restrict__ tgt_c,
    int* __restrict__ hist, float4* __restrict__ cand)
{
    const int inst = blockIdx.x >> 6;
    const float* __restrict__ coords = inst ? tgt_c : src_c;
    int* __restrict__ h = hist + inst * NCELLS;
    float4* __restrict__ cb = cand + inst * N_PTS;
    const int p = ((blockIdx.x & 63) << 8) + threadIdx.x;
    const float* c = coords + (size_t)p * 3;
    const float x = c[0], y = c[1], z = c[2];
    const int dst = atomicAdd(&h[cell_of(x, y, z)], 1);
    cb[dst] = make_float4(x, y, z, __int_as_float(p));
}

__global__ void aabb_kernel(const float4* __restrict__ cand,
                            float* __restrict__ aabb) {
    const int it = blockIdx.x;                 // inst*NTILES + tile
    const int base = (it / NTILES) * N_PTS + (it % NTILES) * TILE;
    const int lane = threadIdx.x;              // 64 threads, 2 pts each
    float4 a = cand[base + lane], b = cand[base + 64 + lane];
    float mnx = fminf(a.x, b.x), mny = fminf(a.y, b.y), mnz = fminf(a.z, b.z);
    float mxx = fmaxf(a.x, b.x), mxy = fmaxf(a.y, b.y), mxz = fmaxf(a.z, b.z);
    #pragma unroll
    for (int off = 1; off < 64; off <<= 1) {
        mnx = fminf(mnx, __shfl_xor(mnx, off));
        mny = fminf(mny, __shfl_xor(mny, off));
        mnz = fminf(mnz, __shfl_xor(mnz, off));
        mxx = fmaxf(mxx, __shfl_xor(mxx, off));
        mxy = fmaxf(mxy, __shfl_xor(mxy, off));
        mxz = fmaxf(mxz, __shfl_xor(mxz, off));
    }
    if (lane == 0) {
        aabb[it * 6 + 0] = mnx; aabb[it * 6 + 1] = mny; aabb[it * 6 + 2] = mnz;
        aabb[it * 6 + 3] = mxx; aabb[it * 6 + 4] = mxy; aabb[it * 6 + 5] = mxz;
    }
}

// Frozen distance chain for candidate C vs query q (do not reorder).
#define DIST_TO(C, q, dout)                                                 \
  { const float csq_ = __fmaf_rn((C).z, (C).z, __fmaf_rn((C).y, (C).y,      \
                                 __fmul_rn((C).x, (C).x)));                 \
    float dot_ = __fmul_rn((C).x, qx[q]);                                   \
    dot_ = __fmaf_rn((C).y, qy[q], dot_);                                   \
    dot_ = __fmaf_rn((C).z, qz[q], dot_);                                   \
    (dout) = __fmaf_rn(dot_, -2.0f, __fadd_rn(qsq[q], csq_)); }

#define LMASK_LT ((1ull << lane) - 1ull)

// Exact 11th-smallest key of 128 wave-held keys (two regs).
#define RADIX11_2(K0, K1, PKOUT)                                            \
  { unsigned pkr_ = 0u;                                                     \
    for (int b_ = 31; b_ >= 0; --b_) {                                      \
      const unsigned mid_ = pkr_ | (1u << b_);                              \
      const int c_ = (int)__popcll(__ballot((K0) < mid_))                   \
                   + (int)__popcll(__ballot((K1) < mid_));                  \
      if (c_ < KK) pkr_ = mid_;                                             \
    }                                                                       \
    (PKOUT) = pkr_; }

// Compact query q's queue to entries <= its exact 11th; W[q] becomes the
// EXACT running 11th (queue holds all candidates <= every past W >= running
// 11th, so the 11 smallest seen are all present). Wave-local, no atomics.
// Same-wave ds read->write ordering is in-order (proven assumption R10+).
#define COMPACT(q)                                                          \
  { const int cc_ = cnt[q];                                                 \
    const int l1_ = 64 + lane;                                              \
    const float cd0_ = (lane < cc_) ? qds[wave][q][lane] : FLT_MAX;         \
    const int   ci0_ = (lane < cc_) ? qis[wave][q][lane] : 0x7fffffff;      \
    const float cd1_ = (l1_ < cc_) ? qds[wave][q][l1_] : FLT_MAX;           \
    const int   ci1_ = (l1_ < cc_) ? qis[wave][q][l1_] : 0x7fffffff;        \
    const unsigned ck0_ = keyf(cd0_), ck1_ = keyf(cd1_);                    \
    unsigned pk_;                                                           \
    RADIX11_2(ck0_, ck1_, pk_);                                             \
    W[q] = unkeyf(pk_);                                                     \
    const bool f0_ = (ck0_ <= pk_) && (lane < cc_);                         \
    const bool f1_ = (ck1_ <= pk_) && (l1_ < cc_);                          \
    const unsigned long long b0_ = __ballot(f0_), b1_ = __ballot(f1_);      \
    const int n0_ = (int)__popcll(b0_);                                     \
    if (f0_) { const int o_ = (int)__popcll(b0_ & LMASK_LT);                \
               qds[wave][q][o_] = cd0_; qis[wave][q][o_] = ci0_; }          \
    if (f1_) { const int o_ = n0_ + (int)__popcll(b1_ & LMASK_LT);          \
               qds[wave][q][o_] = cd1_; qis[wave][q][o_] = ci1_; }          \
    cnt[q] = n0_ + (int)__popcll(b1_); }

// One 64-candidate batch vs the wave's WQ queries: dist -> gate vs W ->
// capacity compact (rare) -> parallel prefix append. No per-candidate
// serial loop, no per-tile radix.
#define APPEND_BATCH(C)                                                     \
  {                                                                         \
    const float cx = (C).x, cy = (C).y, cz = (C).z;                         \
    const int corig = __float_as_int((C).w);                                \
    const float csq = __fmaf_rn(cz, cz, __fmaf_rn(cy, cy,                   \
                                __fmul_rn(cx, cx)));                        \
    _Pragma("unroll")                                                       \
    for (int q = 0; q < WQ; ++q) {                                          \
      float dot = __fmul_rn(cx, qx[q]);                                     \
      dot = __fmaf_rn(cy, qy[q], dot);                                      \
      dot = __fmaf_rn(cz, qz[q], dot);                                      \
      const float sum = __fadd_rn(qsq[q], csq);                             \
      const float d = __fmaf_rn(dot, -2.0f, sum);                           \
      unsigned long long m = __ballot(d <= W[q]);                           \
      if (m) {                                                              \
        if (cnt[q] + (int)__popcll(m) > QCAP) {                             \
          COMPACT(q);                                                       \
          m = __ballot(d <= W[q]);                                          \
        }                                                                   \
        const int base_ = cnt[q];                                           \
        const int o_ = base_ + (int)__popcll(m & LMASK_LT);                 \
        if (((m >> lane) & 1ull) && o_ < QCAP) {                            \
          qds[wave][q][o_] = d; qis[wave][q][o_] = corig;                   \
        }                                                                   \
        cnt[q] = min(base_ + (int)__popcll(m), QCAP);                      \
      }                                                                     \
    }                                                                       \
  }

#define WMAXQ (W[0])

__global__ __launch_bounds__(NTHREADS) void knn_pool_kernel(
    const float* __restrict__ src_f, const float* __restrict__ tgt_f,
    const float4* __restrict__ cand, const float* __restrict__ aabb,
    float* __restrict__ out)
{
    const int inst = blockIdx.x & 1;
    const float* __restrict__ feats = inst ? tgt_f : src_f;
    float* __restrict__ outb = out + (size_t)inst * N_PTS * (2 * C_FEAT);
    const float4* __restrict__ cd = cand + inst * N_PTS;

    const int tid = threadIdx.x, wave = tid >> 6, lane = tid & 63;

    __shared__ float sab[NTILES * 6];                 // 3 KB
    __shared__ unsigned int slist[NWAVES][NTILES];    // packed (lb|tile), 2 KB
    __shared__ float qds[NWAVES][WQ][QCAP];           // 1.5 KB
    __shared__ int   qis[NWAVES][WQ][QCAP];           // 1.5 KB
    for (int i = tid; i < NTILES * 6; i += NTHREADS)
        sab[i] = aabb[inst * NTILES * 6 + i];
    __syncthreads();

    const int q0 = (blockIdx.x >> 1) * QPB + wave * WQ;  // sorted row
    float qx[WQ], qy[WQ], qz[WQ], qsq[WQ];
    int qor[WQ]; float W[WQ]; int cnt[WQ];
    #pragma unroll
    for (int q = 0; q < WQ; ++q) {
        const float4 c = cd[q0 + q];
        qx[q] = c.x; qy[q] = c.y; qz[q] = c.z;
        qor[q] = __float_as_int(c.w);
        qsq[q] = __fmaf_rn(c.z, c.z, __fmaf_rn(c.y, c.y, __fmul_rn(c.x, c.x)));
        W[q] = FLT_MAX;
        cnt[q] = 0;
    }

    const int ownt = q0 / TILE;   // tile containing the queries

    // ---- own tile: radix-select exact 11th distance -> W init + append --
    {
        const float4 c0 = cd[ownt * TILE + lane];
        const float4 c1 = cd[ownt * TILE + 64 + lane];

        unsigned k0[WQ], k1[WQ];
        #pragma unroll
        for (int q = 0; q < WQ; ++q) {
            float d0, d1;
            DIST_TO(c0, q, d0);
            DIST_TO(c1, q, d1);
            k0[q] = keyf(d0);
            k1[q] = keyf(d1);
        }
        #pragma unroll
        for (int q = 0; q < WQ; ++q) {
            unsigned pk_;
            RADIX11_2(k0[q], k1[q], pk_);
            W[q] = unkeyf(pk_);
        }
        // Appends: masks have ~11+ties bits total; fully parallel.
        APPEND_BATCH(c0);
        APPEND_BATCH(c1);
    }

    // ---- zigzag (near->far) survivor list: single-query point-to-box lb --
    // keep tile iff lb - eps <= W (W = exact own-tile 11th; W only shrinks
    // -> skip is safe). Entry packs lb: (bits & ~0xFF) | tile — lb>=0 so
    // uint order == lb order; unpacked rounds DOWN => recheck conservative.
    int nsurv = 0;
    #pragma unroll
    for (int g = 0; g < 4; ++g) {
        const int p = g * 64 + lane;
        const int o = (p >> 1) + 1;
        const int t = (p & 1) ? (ownt - o) : (ownt + o);
        bool ok = (t >= 0) && (t < NTILES);
        float mlb = 0.0f;
        if (ok) {
            const float tmnx = sab[t*6+0], tmny = sab[t*6+1], tmnz = sab[t*6+2];
            const float tmxx = sab[t*6+3], tmxy = sab[t*6+4], tmxz = sab[t*6+5];
            bool any = false;
            mlb = FLT_MAX;
            #pragma unroll
            for (int q = 0; q < WQ; ++q) {
                const float dx = fmaxf(0.f, fmaxf(tmnx - qx[q], qx[q] - tmxx));
                const float dy = fmaxf(0.f, fmaxf(tmny - qy[q], qy[q] - tmxy));
                const float dz = fmaxf(0.f, fmaxf(tmnz - qz[q], qz[q] - tmxz));
                float lb = dx * dx;
                lb = fmaf(dy, dy, lb);
                lb = fmaf(dz, dz, lb);
                any = any || ((lb - 1e-3f) <= W[q]);
                mlb = fminf(mlb, lb);
            }
            ok = any;
        }
        const unsigned long long mk = __ballot(ok);
        if (ok) {
            const int idx = nsurv + (int)__popcll(mk & ((1ull << lane) - 1ull));
            slist[wave][idx] = (__float_as_uint(mlb) & 0xFFFFFF00u) | (unsigned)t;
        }
        nsurv += (int)__popcll(mk);
    }

    // ---- scan survivors: 4-slot prefetch ring + LIVE recheck vs W ----
    float4 T0a, T0b, T1a, T1b, T2a, T2b, T3a, T3b;
    unsigned int u0 = 0, u1 = 0, u2 = 0, u3 = 0;
    {
        u0 = (0 < nsurv) ? slist[wave][0] : (unsigned)ownt;
        const int t0 = (int)(u0 & 0xFFu);
        T0a = cd[t0 * TILE + lane]; T0b = cd[t0 * TILE + 64 + lane];
        u1 = (1 < nsurv) ? slist[wave][1] : (unsigned)ownt;
        const int t1 = (int)(u1 & 0xFFu);
        T1a = cd[t1 * TILE + lane]; T1b = cd[t1 * TILE + 64 + lane];
        u2 = (2 < nsurv) ? slist[wave][2] : (unsigned)ownt;
        const int t2 = (int)(u2 & 0xFFu);
        T2a = cd[t2 * TILE + lane]; T2b = cd[t2 * TILE + 64 + lane];
        u3 = (3 < nsurv) ? slist[wave][3] : (unsigned)ownt;
        const int t3 = (int)(u3 & 0xFFu);
        T3a = cd[t3 * TILE + lane]; T3b = cd[t3 * TILE + 64 + lane];
    }
    #define SCAN_STEP(UA, TA, TB)                                           \
      {                                                                     \
        const unsigned uN = (s + 4 < nsurv) ? slist[wave][s + 4]            \
                                            : (unsigned)ownt;               \
        const int tn = (int)(uN & 0xFFu);                                   \
        if (__uint_as_float(UA & 0xFFFFFF00u) - 1e-3f <= WMAXQ) {           \
            APPEND_BATCH(TA);                                               \
            APPEND_BATCH(TB);                                               \
        }                                                                   \
        UA = uN;                                                            \
        TA = cd[tn * TILE + lane]; TB = cd[tn * TILE + 64 + lane];          \
        ++s;                                                                \
      }
    int s = 0;
    while (s < nsurv) {
        SCAN_STEP(u0, T0a, T0b);
        if (s >= nsurv) break;
        SCAN_STEP(u1, T1a, T1b);
        if (s >= nsurv) break;
        SCAN_STEP(u2, T2a, T2b);
        if (s >= nsurv) break;
        SCAN_STEP(u3, T3a, T3b);
    }
    #undef SCAN_STEP

    // ---- final: per query, exact 11th + compact + bitonic sort + gather --
    // Sorted ascending lex (d, idx): rank 0 = self/near-twin (dropped
    // positionally, as before); ranks 1..10 -> feature columns 0..9.
    float M[WQ];
    #pragma unroll
    for (int q = 0; q < WQ; ++q) {
        COMPACT(q);                       // W[q] = exact final 11th; g>=11
        const int g_ = cnt[q];
        float dl = (lane < g_) ? qds[wave][q][lane] : FLT_MAX;
        int   il = (lane < g_) ? qis[wave][q][lane] : 0x7fffffff;
        #pragma unroll
        for (int k = 2; k <= 64; k <<= 1) {
            #pragma unroll
            for (int j = k >> 1; j > 0; j >>= 1) {
                const float pd = __shfl_xor(dl, j);
                const int   pi = __shfl_xor(il, j);
                const bool keepMin = (((lane & k) == 0) == ((lane & j) == 0));
                const bool mineGt = (dl > pd) || (dl == pd && il > pi);
                const bool take = keepMin ? mineGt : !mineGt;
                dl = take ? pd : dl;
                il = take ? pi : il;
            }
        }
        float fv = -FLT_MAX;
        if (lane >= 1 && lane <= KK - 1)
            fv = feats[(size_t)il * C_FEAT + (lane - 1)];
        #pragma unroll
        for (int off = 1; off < 64; off <<= 1)
            fv = fmaxf(fv, __shfl_xor(fv, off));
        M[q] = fv;
    }

    #pragma unroll
    for (int q = 0; q < WQ; ++q) {
        const int   row = qor[q];
        const float v   = feats[(size_t)row * C_FEAT + lane];
        outb[(size_t)row * (2 * C_FEAT) + lane]          = v;
        outb[(size_t)row * (2 * C_FEAT) + C_FEAT + lane] = M[q] - v;
    }
}

extern "C" void kernel_launch(void* const* d_in, const int* in_sizes, int n_in,
                              void* d_out, int out_size, void* d_ws, size_t ws_size,
                              hipStream_t stream) {
    const float* src_f = (const float*)d_in[0];
    const float* tgt_f = (const float*)d_in[1];
    const float* src_c = (const float*)d_in[2];
    const float* tgt_c = (const float*)d_in[3];
    float* out = (float*)d_out;

    char* ws = (char*)d_ws;
    float4* cand = (float4*)(ws + WS_CAND);
    float*  aabb = (float*) (ws + WS_AABB);
    int*    hist = (int*)   (ws + WS_HIST);

    hipMemsetAsync(hist, 0, 2 * NCELLS * sizeof(int), stream);
    hipLaunchKernelGGL(hist_kernel, dim3(128), dim3(256), 0, stream,
                       src_c, tgt_c, hist);
    hipLaunchKernelGGL(scan_kernel, dim3(2), dim3(1024), 0, stream, hist);
    hipLaunchKernelGGL(scatter_kernel, dim3(128), dim3(256), 0, stream,
                       src_c, tgt_c, hist, cand);
    hipLaunchKernelGGL(aabb_kernel, dim3(2 * NTILES), dim3(64), 0, stream,
                       cand, aabb);
    hipLaunchKernelGGL(knn_pool_kernel, dim3(2 * (N_PTS / QPB)), dim3(NTHREADS),
                       0, stream, src_f, tgt_f, cand, aabb, out);
}